// Round 16
// baseline (287.179 us; speedup 1.0000x reference)
//
#include <hip/hip_runtime.h>

#define E_TOTAL 200000
#define OUTD 5
#define NTILES 3125           // 200000 / 64 exactly, no tail
#define WP_USHORTS 532480     // W0p (262144) + W1p (262144) + W2p (8192)
#define XBF_USHORTS 2560000   // 10000 * 256 bf16 copy of x

typedef __attribute__((ext_vector_type(4))) float f32x4;
typedef __attribute__((ext_vector_type(16))) float f32x16;
typedef __attribute__((ext_vector_type(8))) __bf16 bf16x8;
typedef __attribute__((ext_vector_type(4))) unsigned int u32x4;

static __device__ __forceinline__ unsigned short f2bf(float f) {
  union { float f; unsigned u; } v; v.f = f;
  unsigned u = v.u;
  unsigned r = (u + 0x7FFFu + ((u >> 16) & 1u)) >> 16;   // RNE
  return (unsigned short)r;
}
static __device__ __forceinline__ unsigned short f2bf_cast(float f) {
  __bf16 h = (__bf16)f;                                   // HW cvt, RNE
  return __builtin_bit_cast(unsigned short, h);
}

// ---------------------------------------------------------------------------
// Pack W0,W1 [512x512] into 32x32x16-bf16 fragment order:
//   off = ((wtile*32 + ks)*64 + lane)*8 + j, value = W[k][n]
// W2 [512x5] padded N=16 into 16x16x32 fragment order.
// ws layout (ushort): [0,262144) W0p | [262144,524288) W1p | [524288,532480) W2p
//                     [532480, +2560000) xbf (if ws_size permits)
// ---------------------------------------------------------------------------
__global__ __launch_bounds__(256) void pack_weights(
    const float* __restrict__ W0, const float* __restrict__ W1,
    const float* __restrict__ W2, unsigned short* __restrict__ wp) {
  int tid = blockIdx.x * 256 + threadIdx.x;
  if (tid < 2 * 262144) {
    int sel = tid >> 18;
    int t = tid & 262143;
    int n = t & 511, k = t >> 9;            // coalesced read along n
    const float* W = sel ? W1 : W0;
    float val = W[k * 512 + n];
    int ntile = n >> 5, ks = k >> 4;
    int lane = (((k >> 3) & 1) << 5) | (n & 31);
    int j = k & 7;
    int off = (((ntile * 32 + ks) * 64 + lane) << 3) | j;
    wp[sel * 262144 + off] = f2bf(val);
  } else {
    int t2 = tid - 524288;
    if (t2 < 8192) {                         // W2 padded N=5 -> 16
      int j = t2 & 7, lane = (t2 >> 3) & 63, k0 = t2 >> 9;
      int k = k0 * 32 + ((lane >> 4) << 3) + j;
      int n = lane & 15;
      float val = (n < OUTD) ? W2[k * OUTD + n] : 0.0f;
      wp[524288 + t2] = f2bf(val);
    }
  }
}

// fp32 x -> bf16 copy (one-shot, memory-bound)
__global__ __launch_bounds__(256) void convert_x(
    const float* __restrict__ x, unsigned short* __restrict__ xbf) {
  int i = blockIdx.x * 256 + threadIdx.x;    // 8 elems each
  if (i < 320000) {
    const float4 f0 = *(const float4*)(x + (size_t)i * 8);
    const float4 f1 = *(const float4*)(x + (size_t)i * 8 + 4);
    uint4 pk;
    pk.x = (unsigned)f2bf(f0.x) | ((unsigned)f2bf(f0.y) << 16);
    pk.y = (unsigned)f2bf(f0.z) | ((unsigned)f2bf(f0.w) << 16);
    pk.z = (unsigned)f2bf(f1.x) | ((unsigned)f2bf(f1.y) << 16);
    pk.w = (unsigned)f2bf(f1.z) | ((unsigned)f2bf(f1.w) << 16);
    *(uint4*)(xbf + (size_t)i * 8) = pk;
  }
}

// ---------------------------------------------------------------------------
// Fused edge-MLP, operand-swapped, 4-wave blocks, K-staggered, NT-GATHER:
// identical to the R14 236-us kernel EXCEPT the xbf gather loads are
// NON-TEMPORAL (and out stores likewise). Theory: the 12.8 MB random gather
// stream was churning each XCD's 4 MB L2 and evicting the 1 MB packed-weight
// working set (FETCH_SIZE 51 MB vs ~14 MB ideal = weights refetched 4-5x
// from L3) -> k-loop weight loads at L3/HBM latency (600-900 cyc) that
// depth-1 prefetch can't cover -> the ~40% MfmaUtil invariant of R6-R15.
// nt gather keeps weights L2-resident; loads return ~200 cyc; covered.
// One block = 64 edges, 256 threads (4 waves), 2 blocks/CU.
// Wave w: features w*128..+127 (4 ft-tiles) x 64 edges (2 e-tiles);
// acc 8 x f32x16 (128 AGPR), depth-1 weight prefetch, bias C-init, K-order
// staggered by (b>>3)&31 (sum-invariant).
// LDS: [64][512] bf16 A/H (65536 B, swizzle byte^=(row&7)<<4) + 1280 B obuf.
// Layer 2: 4 waves x 16 edges, pair-mean __shfl_xor(.,1); feature-4 q==1 only.
// ---------------------------------------------------------------------------
template <int XBF>
__global__ __launch_bounds__(256, 2) void edge_mlp(
    const float* __restrict__ x, const unsigned short* __restrict__ xbf,
    const int* __restrict__ eidx,
    const float* __restrict__ b0, const float* __restrict__ b1,
    const float* __restrict__ b2, const unsigned short* __restrict__ wp,
    float* __restrict__ out) {
  __shared__ uint4 ldsv[4096 + 80];           // 65536 + 1280 B
  unsigned char* lds = (unsigned char*)ldsv;
  float* obuf = (float*)(lds + 65536);        // 64*5 f32

  const int tid = threadIdx.x;
  const int lane = tid & 63;
  const int w = tid >> 6;                     // wave 0..3
  const int l31 = lane & 31, h = lane >> 5;
  const int l15 = lane & 15, q = lane >> 4;
  const unsigned t = blockIdx.x;
  const int phase = ((int)t >> 3) & 31;       // per-XCD-position K stagger

  // ---- stage gathered inputs: A[64][512] bf16, cols 0..255 = x[src], 256..511 = x[dst]
  {
    const int p = tid & 7;                    // 8 threads per row, 2 passes
#pragma unroll
    for (int pass = 0; pass < 2; ++pass) {
      const int r = (tid >> 3) + 32 * pass;
      const int e = (int)t * 64 + r;          // grid exact
      const int node = eidx[(p >> 2) * E_TOTAL + e];
      const unsigned rowb = (unsigned)r * 1024;
      const unsigned sx = (unsigned)((r & 7) << 4);
      const unsigned cb0 = (unsigned)((p >> 2) * 512 + (p & 3) * 128);
      if (XBF) {
        const u32x4* s4 = (const u32x4*)(xbf + (size_t)node * 256 + (p & 3) * 64);
#pragma unroll
        for (int jj = 0; jj < 8; ++jj) {
          const int kk = (jj + p) & 7;        // phase by p: conflict-spread writes
          u32x4 pk = __builtin_nontemporal_load(s4 + kk);   // L2-evict-first
          *(u32x4*)(lds + rowb + ((cb0 + (unsigned)kk * 16) ^ sx)) = pk;
        }
      } else {
        const float* s = x + (size_t)node * 256 + (p & 3) * 64;
#pragma unroll
        for (int jj = 0; jj < 8; ++jj) {
          const int kk = (jj + p) & 7;
          const float4 f0 = *(const float4*)(s + kk * 8);
          const float4 f1 = *(const float4*)(s + kk * 8 + 4);
          uint4 pk;
          pk.x = (unsigned)f2bf(f0.x) | ((unsigned)f2bf(f0.y) << 16);
          pk.y = (unsigned)f2bf(f0.z) | ((unsigned)f2bf(f0.w) << 16);
          pk.z = (unsigned)f2bf(f1.x) | ((unsigned)f2bf(f1.y) << 16);
          pk.w = (unsigned)f2bf(f1.z) | ((unsigned)f2bf(f1.w) << 16);
          *(uint4*)(lds + rowb + ((cb0 + (unsigned)kk * 16) ^ sx)) = pk;
        }
      }
    }
  }
  __syncthreads();

  const unsigned sx31 = (unsigned)((l31 & 7) << 4);  // k-loop read & epi swizzle

  // ===== hidden layers =====
#pragma unroll 1
  for (int L = 0; L < 2; ++L) {
    const unsigned short* wl = wp + L * 262144;
    const unsigned short* wbA = wl + (size_t)(4 * w) * 16384 + (size_t)lane * 8;
    const unsigned short* wbB = wbA + 16384;
    const unsigned short* wbC = wbA + 32768;
    const unsigned short* wbD = wbA + 49152;
    const float* bias = L ? b1 : b0;

    // bias C-init: reg 4*qd+rr -> feature w*128 + F*32 + 8*qd + 4*h + rr
    f32x16 aA0, aA1, aB0, aB1, aC0, aC1, aD0, aD1;
#define BINIT(ACC0, ACC1, F)                                                   \
    {                                                                          \
      _Pragma("unroll")                                                        \
      for (int qd = 0; qd < 4; ++qd) {                                         \
        const float4 bq = *(const float4*)(bias + w * 128 + (F) * 32 + 8 * qd + 4 * h); \
        _Pragma("unroll")                                                      \
        for (int rr = 0; rr < 4; ++rr) {                                       \
          (ACC0)[4 * qd + rr] = bq[rr];                                        \
          (ACC1)[4 * qd + rr] = bq[rr];                                        \
        }                                                                      \
      }                                                                        \
    }
    BINIT(aA0, aA1, 0) BINIT(aB0, aB1, 1) BINIT(aC0, aC1, 2) BINIT(aD0, aD1, 3)
#undef BINIT

    bf16x8 cwA = *(const bf16x8*)(wbA + phase * 512);
    bf16x8 cwB = *(const bf16x8*)(wbB + phase * 512);
    bf16x8 cwC = *(const bf16x8*)(wbC + phase * 512);
    bf16x8 cwD = *(const bf16x8*)(wbD + phase * 512);

#pragma unroll 2
    for (int i = 0; i < 32; ++i) {
      const int ks = (i + phase) & 31;        // staggered K order (sum-invariant)
      const int kp = (ks + 1) & 31;           // depth-1 prefetch, branchless wrap
      bf16x8 nwA = *(const bf16x8*)(wbA + kp * 512);
      bf16x8 nwB = *(const bf16x8*)(wbB + kp * 512);
      bf16x8 nwC = *(const bf16x8*)(wbC + kp * 512);
      bf16x8 nwD = *(const bf16x8*)(wbD + kp * 512);
      const unsigned cb = (unsigned)(ks * 32 + h * 16);
      bf16x8 e0 = *(const bf16x8*)(lds + (unsigned)l31 * 1024 + (cb ^ sx31));
      bf16x8 e1 = *(const bf16x8*)(lds + (unsigned)(32 + l31) * 1024 + (cb ^ sx31));
      __builtin_amdgcn_s_setprio(1);
      aA0 = __builtin_amdgcn_mfma_f32_32x32x16_bf16(cwA, e0, aA0, 0, 0, 0);
      aB0 = __builtin_amdgcn_mfma_f32_32x32x16_bf16(cwB, e0, aB0, 0, 0, 0);
      aC0 = __builtin_amdgcn_mfma_f32_32x32x16_bf16(cwC, e0, aC0, 0, 0, 0);
      aD0 = __builtin_amdgcn_mfma_f32_32x32x16_bf16(cwD, e0, aD0, 0, 0, 0);
      aA1 = __builtin_amdgcn_mfma_f32_32x32x16_bf16(cwA, e1, aA1, 0, 0, 0);
      aB1 = __builtin_amdgcn_mfma_f32_32x32x16_bf16(cwB, e1, aB1, 0, 0, 0);
      aC1 = __builtin_amdgcn_mfma_f32_32x32x16_bf16(cwC, e1, aC1, 0, 0, 0);
      aD1 = __builtin_amdgcn_mfma_f32_32x32x16_bf16(cwD, e1, aD1, 0, 0, 0);
      __builtin_amdgcn_s_setprio(0);
      cwA = nwA; cwB = nwB; cwC = nwC; cwD = nwD;
    }

    __syncthreads();   // all waves done reading A/H; only AGPR acc lives across

    // relu + cvt + write H over A, b64 quads.
    // C layout: col(lane&31)=edge, row(reg)=(reg&3)+8*(reg>>2)+4h = feature
    // quad byte col = 256w + 64*F + 16qd + 8h, XOR (edge&7)<<4.
#define EPI_TILE(ACC, F, ET)                                                   \
    {                                                                          \
      const unsigned rowb = (unsigned)((ET) * 32 + l31) * 1024;                \
      const unsigned cbase = (unsigned)(256 * w + 64 * (F) + 8 * h);           \
      _Pragma("unroll")                                                        \
      for (int qd = 0; qd < 4; ++qd) {                                         \
        uint2 pk2;                                                             \
        pk2.x = (unsigned)f2bf_cast(fmaxf((ACC)[4 * qd + 0], 0.f)) |           \
                ((unsigned)f2bf_cast(fmaxf((ACC)[4 * qd + 1], 0.f)) << 16);    \
        pk2.y = (unsigned)f2bf_cast(fmaxf((ACC)[4 * qd + 2], 0.f)) |           \
                ((unsigned)f2bf_cast(fmaxf((ACC)[4 * qd + 3], 0.f)) << 16);    \
        *(uint2*)(lds + rowb + ((cbase + 16u * qd) ^ sx31)) = pk2;             \
      }                                                                        \
    }
    EPI_TILE(aA0, 0, 0) EPI_TILE(aA1, 0, 1)
    EPI_TILE(aB0, 1, 0) EPI_TILE(aB1, 1, 1)
    EPI_TILE(aC0, 2, 0) EPI_TILE(aC1, 2, 1)
    EPI_TILE(aD0, 3, 0) EPI_TILE(aD1, 3, 1)
#undef EPI_TILE
    __syncthreads();
  }

  // ===== layer 2 (swapped, staggered): wave w -> edges w*16..+15, N=16 pad ==
  {
    f32x4 acc2; acc2[0] = 0.f; acc2[1] = 0.f; acc2[2] = 0.f; acc2[3] = 0.f;
    const unsigned short* w2b = wp + 524288 + (size_t)lane * 8;
    const unsigned row = (unsigned)(w * 16 + l15);     // edge (B-operand col)
    const unsigned rsx = (row & 7) << 4;
    const int ph16 = phase & 15;
#pragma unroll
    for (int i = 0; i < 16; ++i) {
      const int k0 = (i + ph16) & 15;         // staggered (sum-invariant)
      bf16x8 eF = *(const bf16x8*)(lds + row * 1024 + (((unsigned)(k0 * 64 + q * 16)) ^ rsx));
      bf16x8 wF = *(const bf16x8*)(w2b + k0 * 512);
      acc2 = __builtin_amdgcn_mfma_f32_16x16x32_bf16(wF, eF, acc2, 0, 0, 0);
    }
    // C: col(l15)=edge, row(q*4+r)=feature. Pair-mean across edges (e, e^1).
    const int e = w * 16 + l15;
#pragma unroll
    for (int r = 0; r < 4; ++r) {
      const float s = __shfl_xor(acc2[r], 1);
      const float m = 0.5f * (acc2[r] + s);
      if (q == 0) {
        obuf[e * OUTD + r] = m + b2[r];
      } else if (q == 1 && r == 0) {          // feature 4 ONLY from q==1
        obuf[e * OUTD + 4] = m + b2[4];
      }
    }
  }
  __syncthreads();

  // ===== coalesced out store, non-temporal (never re-read) =====
  {
    u32x4* dst = (u32x4*)(out + (size_t)t * 320);
    const u32x4* sob = (const u32x4*)obuf;
    if (tid < 80) {
      u32x4 v = sob[tid];
      __builtin_nontemporal_store(v, dst + tid);
    }
  }
}

extern "C" void kernel_launch(void* const* d_in, const int* in_sizes, int n_in,
                              void* d_out, int out_size, void* d_ws, size_t ws_size,
                              hipStream_t stream) {
  const float* x  = (const float*)d_in[0];
  const int* eidx = (const int*)d_in[1];
  const float* W0 = (const float*)d_in[2];
  const float* b0 = (const float*)d_in[3];
  const float* W1 = (const float*)d_in[4];
  const float* b1 = (const float*)d_in[5];
  const float* W2 = (const float*)d_in[6];
  const float* b2 = (const float*)d_in[7];
  float* out = (float*)d_out;
  unsigned short* wp = (unsigned short*)d_ws;
  if (ws_size < (size_t)WP_USHORTS * 2) return;   // ~1.04 MB minimum

  pack_weights<<<2080, 256, 0, stream>>>(W0, W1, W2, wp);
  if (ws_size >= (size_t)(WP_USHORTS + XBF_USHORTS) * 2) {
    unsigned short* xbf = wp + WP_USHORTS;
    convert_x<<<1250, 256, 0, stream>>>(x, xbf);
    edge_mlp<1><<<NTILES, 256, 0, stream>>>(x, xbf, eidx, b0, b1, b2, wp, out);
  } else {
    edge_mlp<0><<<NTILES, 256, 0, stream>>>(x, nullptr, eidx, b0, b1, b2, wp, out);
  }
}

// Round 17
// 241.472 us; speedup vs baseline: 1.1893x; 1.1893x over previous
//
#include <hip/hip_runtime.h>

#define E_TOTAL 200000
#define OUTD 5
#define NT128 1563            // ceil(200000/128); last tile: 64 valid edges
#define WP_USHORTS 532480     // W0p (262144) + W1p (262144) + W2p (8192)
#define XBF_USHORTS 2560000   // 10000 * 256 bf16 copy of x

typedef __attribute__((ext_vector_type(4))) float f32x4;
typedef __attribute__((ext_vector_type(16))) float f32x16;
typedef __attribute__((ext_vector_type(8))) __bf16 bf16x8;

static __device__ __forceinline__ unsigned short f2bf(float f) {
  union { float f; unsigned u; } v; v.f = f;
  unsigned u = v.u;
  unsigned r = (u + 0x7FFFu + ((u >> 16) & 1u)) >> 16;   // RNE
  return (unsigned short)r;
}
static __device__ __forceinline__ unsigned short f2bf_cast(float f) {
  __bf16 h = (__bf16)f;                                   // HW cvt, RNE
  return __builtin_bit_cast(unsigned short, h);
}

// ---------------------------------------------------------------------------
// Pack W0,W1 [512x512] into 32x32x16-bf16 fragment order:
//   off = ((wtile*32 + ks)*64 + lane)*8 + j, value = W[k][n]
// W2 [512x5] padded N=16 into 16x16x32 fragment order.
// ws layout (ushort): [0,262144) W0p | [262144,524288) W1p | [524288,532480) W2p
//                     [532480, +2560000) xbf (if ws_size permits)
// ---------------------------------------------------------------------------
__global__ __launch_bounds__(256) void pack_weights(
    const float* __restrict__ W0, const float* __restrict__ W1,
    const float* __restrict__ W2, unsigned short* __restrict__ wp) {
  int tid = blockIdx.x * 256 + threadIdx.x;
  if (tid < 2 * 262144) {
    int sel = tid >> 18;
    int t = tid & 262143;
    int n = t & 511, k = t >> 9;            // coalesced read along n
    const float* W = sel ? W1 : W0;
    float val = W[k * 512 + n];
    int ntile = n >> 5, ks = k >> 4;
    int lane = (((k >> 3) & 1) << 5) | (n & 31);
    int j = k & 7;
    int off = (((ntile * 32 + ks) * 64 + lane) << 3) | j;
    wp[sel * 262144 + off] = f2bf(val);
  } else {
    int t2 = tid - 524288;
    if (t2 < 8192) {                         // W2 padded N=5 -> 16
      int j = t2 & 7, lane = (t2 >> 3) & 63, k0 = t2 >> 9;
      int k = k0 * 32 + ((lane >> 4) << 3) + j;
      int n = lane & 15;
      float val = (n < OUTD) ? W2[k * OUTD + n] : 0.0f;
      wp[524288 + t2] = f2bf(val);
    }
  }
}

// fp32 x -> bf16 copy (one-shot, memory-bound)
__global__ __launch_bounds__(256) void convert_x(
    const float* __restrict__ x, unsigned short* __restrict__ xbf) {
  int i = blockIdx.x * 256 + threadIdx.x;    // 8 elems each
  if (i < 320000) {
    const float4 f0 = *(const float4*)(x + (size_t)i * 8);
    const float4 f1 = *(const float4*)(x + (size_t)i * 8 + 4);
    uint4 pk;
    pk.x = (unsigned)f2bf(f0.x) | ((unsigned)f2bf(f0.y) << 16);
    pk.y = (unsigned)f2bf(f0.z) | ((unsigned)f2bf(f0.w) << 16);
    pk.z = (unsigned)f2bf(f1.x) | ((unsigned)f2bf(f1.y) << 16);
    pk.w = (unsigned)f2bf(f1.z) | ((unsigned)f2bf(f1.w) << 16);
    *(uint4*)(xbf + (size_t)i * 8) = pk;
  }
}

// ---------------------------------------------------------------------------
// Fused edge-MLP, operand-swapped, WIDE-EDGE wave tiles (2ft x 4et):
// VMEM-BW thesis: every prior config streamed >=2 KB of weights per 256
// MFMA-pipe-cycles per wave (32-64 B/cyc/CU through TA/L1) -> at the per-CU
// L2-read throughput ceiling -> the invariant ~40% MfmaUtil of R6-R16.
// This kernel HALVES the ratio: wave = 64 features x 128 edges -> per k-step
// 2 weight loads (1 KB) feed 8 MFMAs (256 pipe-cyc) = 16 B/cyc/CU.
// One block = 128 edges, 512 threads (8 waves), 1 block/CU.
// Wave w: features w*64..+63 (2 ft-tiles) x 128 edges (4 e-tiles);
// acc 8 x f32x16 (128 AGPR), depth-1 weight prefetch, bias C-init, K-order
// staggered by (b>>3)&31 (sum-invariant). 4 ds_read_b128/step (128 B/cyc/CU
// vs 256 peak). LDS: [128][512] bf16 A/H (131072 B, swz byte^=(row&7)<<4)
// + 2560 B obuf. Layer 2: 8 waves x 16 edges, pair-mean __shfl_xor(.,1);
// feature-4 written only by q==1.
// ---------------------------------------------------------------------------
template <int XBF>
__global__ __launch_bounds__(512, 2) void edge_mlp(
    const float* __restrict__ x, const unsigned short* __restrict__ xbf,
    const int* __restrict__ eidx,
    const float* __restrict__ b0, const float* __restrict__ b1,
    const float* __restrict__ b2, const unsigned short* __restrict__ wp,
    float* __restrict__ out) {
  __shared__ uint4 ldsv[8192 + 160];          // 131072 + 2560 B
  unsigned char* lds = (unsigned char*)ldsv;
  float* obuf = (float*)(lds + 131072);       // 128*5 f32

  const int tid = threadIdx.x;
  const int lane = tid & 63;
  const int w = tid >> 6;                     // wave 0..7
  const int l31 = lane & 31, h = lane >> 5;
  const int l15 = lane & 15, q = lane >> 4;
  const unsigned t = blockIdx.x;
  const int phase = ((int)t >> 3) & 31;       // per-XCD-position K stagger

  // ---- stage gathered inputs: A[128][512] bf16, cols 0..255=x[src], 256..511=x[dst]
  {
    const int p = tid & 7;                    // 8 threads per row, 2 passes
#pragma unroll
    for (int pass = 0; pass < 2; ++pass) {
      const int r = (tid >> 3) + 64 * pass;
      int e = (int)t * 128 + r; if (e >= E_TOTAL) e = E_TOTAL - 1;
      const int node = eidx[(p >> 2) * E_TOTAL + e];
      const unsigned rowb = (unsigned)r * 1024;
      const unsigned sx = (unsigned)((r & 7) << 4);
      const unsigned cb0 = (unsigned)((p >> 2) * 512 + (p & 3) * 128);
      if (XBF) {
        const unsigned short* s = xbf + (size_t)node * 256 + (p & 3) * 64;
#pragma unroll
        for (int jj = 0; jj < 8; ++jj) {
          const int kk = (jj + p) & 7;        // phase by p: conflict-spread writes
          uint4 pk = *(const uint4*)(s + kk * 8);
          *(uint4*)(lds + rowb + ((cb0 + (unsigned)kk * 16) ^ sx)) = pk;
        }
      } else {
        const float* s = x + (size_t)node * 256 + (p & 3) * 64;
#pragma unroll
        for (int jj = 0; jj < 8; ++jj) {
          const int kk = (jj + p) & 7;
          const float4 f0 = *(const float4*)(s + kk * 8);
          const float4 f1 = *(const float4*)(s + kk * 8 + 4);
          uint4 pk;
          pk.x = (unsigned)f2bf(f0.x) | ((unsigned)f2bf(f0.y) << 16);
          pk.y = (unsigned)f2bf(f0.z) | ((unsigned)f2bf(f0.w) << 16);
          pk.z = (unsigned)f2bf(f1.x) | ((unsigned)f2bf(f1.y) << 16);
          pk.w = (unsigned)f2bf(f1.z) | ((unsigned)f2bf(f1.w) << 16);
          *(uint4*)(lds + rowb + ((cb0 + (unsigned)kk * 16) ^ sx)) = pk;
        }
      }
    }
  }
  __syncthreads();

  const unsigned sx31 = (unsigned)((l31 & 7) << 4);  // k-loop read & epi swizzle
  const unsigned short* w2b = wp + 524288 + (size_t)lane * 8;

  // ===== hidden layers =====
#pragma unroll 1
  for (int L = 0; L < 2; ++L) {
    const unsigned short* wl = wp + L * 262144;
    const unsigned short* wbA = wl + (size_t)(2 * w) * 16384 + (size_t)lane * 8;
    const unsigned short* wbB = wbA + 16384;
    const float* bias = L ? b1 : b0;

    // bias C-init: reg 4*qd+rr -> feature w*64 + F*32 + 8*qd + 4*h + rr
    f32x16 aA0, aA1, aA2, aA3, aB0, aB1, aB2, aB3;   // acc[ftile][etile]
#define BINIT(A0, A1, A2, A3, F)                                               \
    {                                                                          \
      _Pragma("unroll")                                                        \
      for (int qd = 0; qd < 4; ++qd) {                                         \
        const float4 bq = *(const float4*)(bias + w * 64 + (F) * 32 + 8 * qd + 4 * h); \
        _Pragma("unroll")                                                      \
        for (int rr = 0; rr < 4; ++rr) {                                       \
          (A0)[4 * qd + rr] = bq[rr]; (A1)[4 * qd + rr] = bq[rr];              \
          (A2)[4 * qd + rr] = bq[rr]; (A3)[4 * qd + rr] = bq[rr];              \
        }                                                                      \
      }                                                                        \
    }
    BINIT(aA0, aA1, aA2, aA3, 0) BINIT(aB0, aB1, aB2, aB3, 1)
#undef BINIT

    bf16x8 cwA = *(const bf16x8*)(wbA + phase * 512);
    bf16x8 cwB = *(const bf16x8*)(wbB + phase * 512);

#pragma unroll 2
    for (int i = 0; i < 32; ++i) {
      const int ks = (i + phase) & 31;        // staggered K order (sum-invariant)
      const int kp = (ks + 1) & 31;           // depth-1 prefetch, branchless wrap
      bf16x8 nwA = *(const bf16x8*)(wbA + kp * 512);
      bf16x8 nwB = *(const bf16x8*)(wbB + kp * 512);
      const unsigned cb = (unsigned)(ks * 32 + h * 16);
      bf16x8 e0 = *(const bf16x8*)(lds + (unsigned)l31 * 1024 + (cb ^ sx31));
      bf16x8 e1 = *(const bf16x8*)(lds + (unsigned)(32 + l31) * 1024 + (cb ^ sx31));
      bf16x8 e2 = *(const bf16x8*)(lds + (unsigned)(64 + l31) * 1024 + (cb ^ sx31));
      bf16x8 e3 = *(const bf16x8*)(lds + (unsigned)(96 + l31) * 1024 + (cb ^ sx31));
      __builtin_amdgcn_s_setprio(1);
      aA0 = __builtin_amdgcn_mfma_f32_32x32x16_bf16(cwA, e0, aA0, 0, 0, 0);
      aB0 = __builtin_amdgcn_mfma_f32_32x32x16_bf16(cwB, e0, aB0, 0, 0, 0);
      aA1 = __builtin_amdgcn_mfma_f32_32x32x16_bf16(cwA, e1, aA1, 0, 0, 0);
      aB1 = __builtin_amdgcn_mfma_f32_32x32x16_bf16(cwB, e1, aB1, 0, 0, 0);
      aA2 = __builtin_amdgcn_mfma_f32_32x32x16_bf16(cwA, e2, aA2, 0, 0, 0);
      aB2 = __builtin_amdgcn_mfma_f32_32x32x16_bf16(cwB, e2, aB2, 0, 0, 0);
      aA3 = __builtin_amdgcn_mfma_f32_32x32x16_bf16(cwA, e3, aA3, 0, 0, 0);
      aB3 = __builtin_amdgcn_mfma_f32_32x32x16_bf16(cwB, e3, aB3, 0, 0, 0);
      __builtin_amdgcn_s_setprio(0);
      cwA = nwA; cwB = nwB;
    }

    __syncthreads();   // all waves done reading A/H; only AGPR acc lives across

    // relu + cvt + write H over A, b64 quads.
    // C layout: col(lane&31)=edge, row(reg)=(reg&3)+8*(reg>>2)+4h = feature
    // quad byte col = 128w + 64*F + 16qd + 8h, XOR (edge&7)<<4.
#define EPI_TILE(ACC, F, ET)                                                   \
    {                                                                          \
      const unsigned rowb = (unsigned)((ET) * 32 + l31) * 1024;                \
      const unsigned cbase = (unsigned)(128 * w + 64 * (F) + 8 * h);           \
      _Pragma("unroll")                                                        \
      for (int qd = 0; qd < 4; ++qd) {                                         \
        uint2 pk2;                                                             \
        pk2.x = (unsigned)f2bf_cast(fmaxf((ACC)[4 * qd + 0], 0.f)) |           \
                ((unsigned)f2bf_cast(fmaxf((ACC)[4 * qd + 1], 0.f)) << 16);    \
        pk2.y = (unsigned)f2bf_cast(fmaxf((ACC)[4 * qd + 2], 0.f)) |           \
                ((unsigned)f2bf_cast(fmaxf((ACC)[4 * qd + 3], 0.f)) << 16);    \
        *(uint2*)(lds + rowb + ((cbase + 16u * qd) ^ sx31)) = pk2;             \
      }                                                                        \
    }
    EPI_TILE(aA0, 0, 0) EPI_TILE(aA1, 0, 1) EPI_TILE(aA2, 0, 2) EPI_TILE(aA3, 0, 3)
    EPI_TILE(aB0, 1, 0) EPI_TILE(aB1, 1, 1) EPI_TILE(aB2, 1, 2) EPI_TILE(aB3, 1, 3)
#undef EPI_TILE
    __syncthreads();
  }

  // ===== layer 2 (swapped, staggered): wave w -> edges w*16..+15, N=16 pad ==
  {
    f32x4 acc2; acc2[0] = 0.f; acc2[1] = 0.f; acc2[2] = 0.f; acc2[3] = 0.f;
    const unsigned row = (unsigned)(w * 16 + l15);     // edge (B-operand col)
    const unsigned rsx = (row & 7) << 4;
    const int ph16 = phase & 15;
#pragma unroll
    for (int i = 0; i < 16; ++i) {
      const int k0 = (i + ph16) & 15;         // staggered (sum-invariant)
      bf16x8 eF = *(const bf16x8*)(lds + row * 1024 + (((unsigned)(k0 * 64 + q * 16)) ^ rsx));
      bf16x8 wF = *(const bf16x8*)(w2b + k0 * 512);
      acc2 = __builtin_amdgcn_mfma_f32_16x16x32_bf16(wF, eF, acc2, 0, 0, 0);
    }
    // C: col(l15)=edge, row(q*4+r)=feature. Pair-mean across edges (e, e^1).
    const int e = w * 16 + l15;
#pragma unroll
    for (int r = 0; r < 4; ++r) {
      const float s = __shfl_xor(acc2[r], 1);
      const float m = 0.5f * (acc2[r] + s);
      if (q == 0) {
        obuf[e * OUTD + r] = m + b2[r];
      } else if (q == 1 && r == 0) {          // feature 4 ONLY from q==1
        obuf[e * OUTD + 4] = m + b2[4];
      }
    }
  }
  __syncthreads();

  // ===== coalesced out store (full 64B lines) =====
  {
    const int ve = (t == NT128 - 1) ? 64 : 128;
    const int nv4 = (ve * OUTD) >> 2;         // 160 or 80 uint4
    uint4* dst = (uint4*)(out + (size_t)t * 640);
    const uint4* sob = (const uint4*)obuf;
    if (tid < nv4) dst[tid] = sob[tid];
  }
}

extern "C" void kernel_launch(void* const* d_in, const int* in_sizes, int n_in,
                              void* d_out, int out_size, void* d_ws, size_t ws_size,
                              hipStream_t stream) {
  const float* x  = (const float*)d_in[0];
  const int* eidx = (const int*)d_in[1];
  const float* W0 = (const float*)d_in[2];
  const float* b0 = (const float*)d_in[3];
  const float* W1 = (const float*)d_in[4];
  const float* b1 = (const float*)d_in[5];
  const float* W2 = (const float*)d_in[6];
  const float* b2 = (const float*)d_in[7];
  float* out = (float*)d_out;
  unsigned short* wp = (unsigned short*)d_ws;
  if (ws_size < (size_t)WP_USHORTS * 2) return;   // ~1.04 MB minimum

  pack_weights<<<2080, 256, 0, stream>>>(W0, W1, W2, wp);
  if (ws_size >= (size_t)(WP_USHORTS + XBF_USHORTS) * 2) {
    unsigned short* xbf = wp + WP_USHORTS;
    convert_x<<<1250, 256, 0, stream>>>(x, xbf);
    edge_mlp<1><<<NT128, 512, 0, stream>>>(x, xbf, eidx, b0, b1, b2, wp, out);
  } else {
    edge_mlp<0><<<NT128, 512, 0, stream>>>(x, nullptr, eidx, b0, b1, b2, wp, out);
  }
}

// Round 18
// 237.819 us; speedup vs baseline: 1.2076x; 1.0154x over previous
//
#include <hip/hip_runtime.h>

#define E_TOTAL 200000
#define OUTD 5
#define NTILES 3125           // 200000 / 64 exactly, no tail
#define WP_USHORTS 532480     // W0p (262144) + W1p (262144) + W2p (8192)
#define XBF_USHORTS 2560000   // 10000 * 256 bf16 copy of x

typedef __attribute__((ext_vector_type(4))) float f32x4;
typedef __attribute__((ext_vector_type(16))) float f32x16;
typedef __attribute__((ext_vector_type(8))) __bf16 bf16x8;

static __device__ __forceinline__ unsigned short f2bf(float f) {
  union { float f; unsigned u; } v; v.f = f;
  unsigned u = v.u;
  unsigned r = (u + 0x7FFFu + ((u >> 16) & 1u)) >> 16;   // RNE
  return (unsigned short)r;
}
static __device__ __forceinline__ unsigned short f2bf_cast(float f) {
  __bf16 h = (__bf16)f;                                   // HW cvt, RNE
  return __builtin_bit_cast(unsigned short, h);
}

// ---------------------------------------------------------------------------
// Pack W0,W1 [512x512] into 32x32x16-bf16 fragment order:
//   off = ((wtile*32 + ks)*64 + lane)*8 + j, value = W[k][n]
// W2 [512x5] padded N=16 into 16x16x32 fragment order.
// ws layout (ushort): [0,262144) W0p | [262144,524288) W1p | [524288,532480) W2p
//                     [532480, +2560000) xbf (if ws_size permits)
// ---------------------------------------------------------------------------
__global__ __launch_bounds__(256) void pack_weights(
    const float* __restrict__ W0, const float* __restrict__ W1,
    const float* __restrict__ W2, unsigned short* __restrict__ wp) {
  int tid = blockIdx.x * 256 + threadIdx.x;
  if (tid < 2 * 262144) {
    int sel = tid >> 18;
    int t = tid & 262143;
    int n = t & 511, k = t >> 9;            // coalesced read along n
    const float* W = sel ? W1 : W0;
    float val = W[k * 512 + n];
    int ntile = n >> 5, ks = k >> 4;
    int lane = (((k >> 3) & 1) << 5) | (n & 31);
    int j = k & 7;
    int off = (((ntile * 32 + ks) * 64 + lane) << 3) | j;
    wp[sel * 262144 + off] = f2bf(val);
  } else {
    int t2 = tid - 524288;
    if (t2 < 8192) {                         // W2 padded N=5 -> 16
      int j = t2 & 7, lane = (t2 >> 3) & 63, k0 = t2 >> 9;
      int k = k0 * 32 + ((lane >> 4) << 3) + j;
      int n = lane & 15;
      float val = (n < OUTD) ? W2[k * OUTD + n] : 0.0f;
      wp[524288 + t2] = f2bf(val);
    }
  }
}

// fp32 x -> bf16 copy (one-shot, memory-bound)
__global__ __launch_bounds__(256) void convert_x(
    const float* __restrict__ x, unsigned short* __restrict__ xbf) {
  int i = blockIdx.x * 256 + threadIdx.x;    // 8 elems each
  if (i < 320000) {
    const float4 f0 = *(const float4*)(x + (size_t)i * 8);
    const float4 f1 = *(const float4*)(x + (size_t)i * 8 + 4);
    uint4 pk;
    pk.x = (unsigned)f2bf(f0.x) | ((unsigned)f2bf(f0.y) << 16);
    pk.y = (unsigned)f2bf(f0.z) | ((unsigned)f2bf(f0.w) << 16);
    pk.z = (unsigned)f2bf(f1.x) | ((unsigned)f2bf(f1.y) << 16);
    pk.w = (unsigned)f2bf(f1.z) | ((unsigned)f2bf(f1.w) << 16);
    *(uint4*)(xbf + (size_t)i * 8) = pk;
  }
}

// ---------------------------------------------------------------------------
// Fused edge-MLP, operand-swapped, 4-wave blocks, K-staggered, E-PIPELINED:
// identical to the R14 236-us kernel EXCEPT (1) the LDS edge-fragment reads
// are software-pipelined ONE ITERATION AHEAD (reads issue ~600 cyc before
// their consuming MFMAs -> the lgkmcnt wait leaves the per-iteration
// critical path; the last remaining never-varied element of the k-loop),
// and (2) s_setprio removed (all-waves-prio-1 is arbitration-neutral and
// m190 measured it NEGATIVE on lockstep GEMM structures).
// One block = 64 edges, 256 threads (4 waves), 2 blocks/CU.
// Wave w: features w*128..+127 (4 ft-tiles) x 64 edges (2 e-tiles);
// acc 8 x f32x16 (128 AGPR), depth-1 weight prefetch + 1-ahead e-frags
// (~120 VGPR), bias C-init, K-order staggered by (b>>3)&31.
// LDS: [64][512] bf16 A/H (65536 B, swizzle byte^=(row&7)<<4) + 1280 B obuf.
// Layer 2: 4 waves x 16 edges, pair-mean __shfl_xor(.,1); feature-4 q==1 only.
// ---------------------------------------------------------------------------
template <int XBF>
__global__ __launch_bounds__(256, 2) void edge_mlp(
    const float* __restrict__ x, const unsigned short* __restrict__ xbf,
    const int* __restrict__ eidx,
    const float* __restrict__ b0, const float* __restrict__ b1,
    const float* __restrict__ b2, const unsigned short* __restrict__ wp,
    float* __restrict__ out) {
  __shared__ uint4 ldsv[4096 + 80];           // 65536 + 1280 B
  unsigned char* lds = (unsigned char*)ldsv;
  float* obuf = (float*)(lds + 65536);        // 64*5 f32

  const int tid = threadIdx.x;
  const int lane = tid & 63;
  const int w = tid >> 6;                     // wave 0..3
  const int l31 = lane & 31, h = lane >> 5;
  const int l15 = lane & 15, q = lane >> 4;
  const unsigned t = blockIdx.x;
  const int phase = ((int)t >> 3) & 31;       // per-XCD-position K stagger

  // ---- stage gathered inputs: A[64][512] bf16, cols 0..255 = x[src], 256..511 = x[dst]
  {
    const int p = tid & 7;                    // 8 threads per row, 2 passes
#pragma unroll
    for (int pass = 0; pass < 2; ++pass) {
      const int r = (tid >> 3) + 32 * pass;
      const int e = (int)t * 64 + r;          // grid exact
      const int node = eidx[(p >> 2) * E_TOTAL + e];
      const unsigned rowb = (unsigned)r * 1024;
      const unsigned sx = (unsigned)((r & 7) << 4);
      const unsigned cb0 = (unsigned)((p >> 2) * 512 + (p & 3) * 128);
      if (XBF) {
        const unsigned short* s = xbf + (size_t)node * 256 + (p & 3) * 64;
#pragma unroll
        for (int jj = 0; jj < 8; ++jj) {
          const int kk = (jj + p) & 7;        // phase by p: conflict-spread writes
          uint4 pk = *(const uint4*)(s + kk * 8);
          *(uint4*)(lds + rowb + ((cb0 + (unsigned)kk * 16) ^ sx)) = pk;
        }
      } else {
        const float* s = x + (size_t)node * 256 + (p & 3) * 64;
#pragma unroll
        for (int jj = 0; jj < 8; ++jj) {
          const int kk = (jj + p) & 7;
          const float4 f0 = *(const float4*)(s + kk * 8);
          const float4 f1 = *(const float4*)(s + kk * 8 + 4);
          uint4 pk;
          pk.x = (unsigned)f2bf(f0.x) | ((unsigned)f2bf(f0.y) << 16);
          pk.y = (unsigned)f2bf(f0.z) | ((unsigned)f2bf(f0.w) << 16);
          pk.z = (unsigned)f2bf(f1.x) | ((unsigned)f2bf(f1.y) << 16);
          pk.w = (unsigned)f2bf(f1.z) | ((unsigned)f2bf(f1.w) << 16);
          *(uint4*)(lds + rowb + ((cb0 + (unsigned)kk * 16) ^ sx)) = pk;
        }
      }
    }
  }
  __syncthreads();

  const unsigned sx31 = (unsigned)((l31 & 7) << 4);  // k-loop read & epi swizzle
  const unsigned er0 = (unsigned)l31 * 1024;         // e-tile row bases
  const unsigned er1 = (unsigned)(32 + l31) * 1024;

  // ===== hidden layers =====
#pragma unroll 1
  for (int L = 0; L < 2; ++L) {
    const unsigned short* wl = wp + L * 262144;
    const unsigned short* wbA = wl + (size_t)(4 * w) * 16384 + (size_t)lane * 8;
    const unsigned short* wbB = wbA + 16384;
    const unsigned short* wbC = wbA + 32768;
    const unsigned short* wbD = wbA + 49152;
    const float* bias = L ? b1 : b0;

    // bias C-init: reg 4*qd+rr -> feature w*128 + F*32 + 8*qd + 4*h + rr
    f32x16 aA0, aA1, aB0, aB1, aC0, aC1, aD0, aD1;
#define BINIT(ACC0, ACC1, F)                                                   \
    {                                                                          \
      _Pragma("unroll")                                                        \
      for (int qd = 0; qd < 4; ++qd) {                                         \
        const float4 bq = *(const float4*)(bias + w * 128 + (F) * 32 + 8 * qd + 4 * h); \
        _Pragma("unroll")                                                      \
        for (int rr = 0; rr < 4; ++rr) {                                       \
          (ACC0)[4 * qd + rr] = bq[rr];                                        \
          (ACC1)[4 * qd + rr] = bq[rr];                                        \
        }                                                                      \
      }                                                                        \
    }
    BINIT(aA0, aA1, 0) BINIT(aB0, aB1, 1) BINIT(aC0, aC1, 2) BINIT(aD0, aD1, 3)
#undef BINIT

    // prologue: weights + e-frags for first iteration (ks = phase)
    bf16x8 cwA = *(const bf16x8*)(wbA + phase * 512);
    bf16x8 cwB = *(const bf16x8*)(wbB + phase * 512);
    bf16x8 cwC = *(const bf16x8*)(wbC + phase * 512);
    bf16x8 cwD = *(const bf16x8*)(wbD + phase * 512);
    const unsigned cb00 = (unsigned)(phase * 32 + h * 16);
    bf16x8 e0 = *(const bf16x8*)(lds + er0 + (cb00 ^ sx31));
    bf16x8 e1 = *(const bf16x8*)(lds + er1 + (cb00 ^ sx31));

#pragma unroll 2
    for (int i = 0; i < 32; ++i) {
      const int ks = (i + phase) & 31;        // staggered K order (sum-invariant)
      const int kp = (ks + 1) & 31;           // next iteration's K index
      // issue next iteration's weight loads AND e-frag reads up front;
      // their waits fall a full iteration (~600 cyc) later
      bf16x8 nwA = *(const bf16x8*)(wbA + kp * 512);
      bf16x8 nwB = *(const bf16x8*)(wbB + kp * 512);
      bf16x8 nwC = *(const bf16x8*)(wbC + kp * 512);
      bf16x8 nwD = *(const bf16x8*)(wbD + kp * 512);
      const unsigned cbn = (unsigned)(kp * 32 + h * 16);
      bf16x8 ne0 = *(const bf16x8*)(lds + er0 + (cbn ^ sx31));
      bf16x8 ne1 = *(const bf16x8*)(lds + er1 + (cbn ^ sx31));
      aA0 = __builtin_amdgcn_mfma_f32_32x32x16_bf16(cwA, e0, aA0, 0, 0, 0);
      aB0 = __builtin_amdgcn_mfma_f32_32x32x16_bf16(cwB, e0, aB0, 0, 0, 0);
      aC0 = __builtin_amdgcn_mfma_f32_32x32x16_bf16(cwC, e0, aC0, 0, 0, 0);
      aD0 = __builtin_amdgcn_mfma_f32_32x32x16_bf16(cwD, e0, aD0, 0, 0, 0);
      aA1 = __builtin_amdgcn_mfma_f32_32x32x16_bf16(cwA, e1, aA1, 0, 0, 0);
      aB1 = __builtin_amdgcn_mfma_f32_32x32x16_bf16(cwB, e1, aB1, 0, 0, 0);
      aC1 = __builtin_amdgcn_mfma_f32_32x32x16_bf16(cwC, e1, aC1, 0, 0, 0);
      aD1 = __builtin_amdgcn_mfma_f32_32x32x16_bf16(cwD, e1, aD1, 0, 0, 0);
      cwA = nwA; cwB = nwB; cwC = nwC; cwD = nwD;
      e0 = ne0; e1 = ne1;
    }

    __syncthreads();   // all waves done reading A/H; only AGPR acc lives across

    // relu + cvt + write H over A, b64 quads.
    // C layout: col(lane&31)=edge, row(reg)=(reg&3)+8*(reg>>2)+4h = feature
    // quad byte col = 256w + 64*F + 16qd + 8h, XOR (edge&7)<<4.
#define EPI_TILE(ACC, F, ET)                                                   \
    {                                                                          \
      const unsigned rowb = (unsigned)((ET) * 32 + l31) * 1024;                \
      const unsigned cbase = (unsigned)(256 * w + 64 * (F) + 8 * h);           \
      _Pragma("unroll")                                                        \
      for (int qd = 0; qd < 4; ++qd) {                                         \
        uint2 pk2;                                                             \
        pk2.x = (unsigned)f2bf_cast(fmaxf((ACC)[4 * qd + 0], 0.f)) |           \
                ((unsigned)f2bf_cast(fmaxf((ACC)[4 * qd + 1], 0.f)) << 16);    \
        pk2.y = (unsigned)f2bf_cast(fmaxf((ACC)[4 * qd + 2], 0.f)) |           \
                ((unsigned)f2bf_cast(fmaxf((ACC)[4 * qd + 3], 0.f)) << 16);    \
        *(uint2*)(lds + rowb + ((cbase + 16u * qd) ^ sx31)) = pk2;             \
      }                                                                        \
    }
    EPI_TILE(aA0, 0, 0) EPI_TILE(aA1, 0, 1)
    EPI_TILE(aB0, 1, 0) EPI_TILE(aB1, 1, 1)
    EPI_TILE(aC0, 2, 0) EPI_TILE(aC1, 2, 1)
    EPI_TILE(aD0, 3, 0) EPI_TILE(aD1, 3, 1)
#undef EPI_TILE
    __syncthreads();
  }

  // ===== layer 2 (swapped, staggered): wave w -> edges w*16..+15, N=16 pad ==
  {
    f32x4 acc2; acc2[0] = 0.f; acc2[1] = 0.f; acc2[2] = 0.f; acc2[3] = 0.f;
    const unsigned short* w2b = wp + 524288 + (size_t)lane * 8;
    const unsigned row = (unsigned)(w * 16 + l15);     // edge (B-operand col)
    const unsigned rsx = (row & 7) << 4;
    const int ph16 = phase & 15;
#pragma unroll
    for (int i = 0; i < 16; ++i) {
      const int k0 = (i + ph16) & 15;         // staggered (sum-invariant)
      bf16x8 eF = *(const bf16x8*)(lds + row * 1024 + (((unsigned)(k0 * 64 + q * 16)) ^ rsx));
      bf16x8 wF = *(const bf16x8*)(w2b + k0 * 512);
      acc2 = __builtin_amdgcn_mfma_f32_16x16x32_bf16(wF, eF, acc2, 0, 0, 0);
    }
    // C: col(l15)=edge, row(q*4+r)=feature. Pair-mean across edges (e, e^1).
    const int e = w * 16 + l15;
#pragma unroll
    for (int r = 0; r < 4; ++r) {
      const float s = __shfl_xor(acc2[r], 1);
      const float m = 0.5f * (acc2[r] + s);
      if (q == 0) {
        obuf[e * OUTD + r] = m + b2[r];
      } else if (q == 1 && r == 0) {          // feature 4 ONLY from q==1
        obuf[e * OUTD + 4] = m + b2[4];
      }
    }
  }
  __syncthreads();

  // ===== coalesced out store (full 64B lines; 64*5*4B = 20 lines) =====
  {
    uint4* dst = (uint4*)(out + (size_t)t * 320);
    const uint4* sob = (const uint4*)obuf;
    if (tid < 80) dst[tid] = sob[tid];
  }
}

extern "C" void kernel_launch(void* const* d_in, const int* in_sizes, int n_in,
                              void* d_out, int out_size, void* d_ws, size_t ws_size,
                              hipStream_t stream) {
  const float* x  = (const float*)d_in[0];
  const int* eidx = (const int*)d_in[1];
  const float* W0 = (const float*)d_in[2];
  const float* b0 = (const float*)d_in[3];
  const float* W1 = (const float*)d_in[4];
  const float* b1 = (const float*)d_in[5];
  const float* W2 = (const float*)d_in[6];
  const float* b2 = (const float*)d_in[7];
  float* out = (float*)d_out;
  unsigned short* wp = (unsigned short*)d_ws;
  if (ws_size < (size_t)WP_USHORTS * 2) return;   // ~1.04 MB minimum

  pack_weights<<<2080, 256, 0, stream>>>(W0, W1, W2, wp);
  if (ws_size >= (size_t)(WP_USHORTS + XBF_USHORTS) * 2) {
    unsigned short* xbf = wp + WP_USHORTS;
    convert_x<<<1250, 256, 0, stream>>>(x, xbf);
    edge_mlp<1><<<NTILES, 256, 0, stream>>>(x, xbf, eidx, b0, b1, b2, wp, out);
  } else {
    edge_mlp<0><<<NTILES, 256, 0, stream>>>(x, nullptr, eidx, b0, b1, b2, wp, out);
  }
}

// Round 19
// 229.273 us; speedup vs baseline: 1.2526x; 1.0373x over previous
//
#include <hip/hip_runtime.h>

#define E_TOTAL 200000
#define OUTD 5
#define NTILES 3125           // 200000 / 64 exactly, no tail
#define WP_USHORTS 532480     // W0p (262144) + W1p (262144) + W2p (8192)
#define YAB_USHORTS 10240000  // 10000 nodes x 1024 (ya|yb) bf16
#define WS_NEED ((size_t)(WP_USHORTS + YAB_USHORTS) * 2)

typedef __attribute__((ext_vector_type(4))) float f32x4;
typedef __attribute__((ext_vector_type(16))) float f32x16;
typedef __attribute__((ext_vector_type(8))) __bf16 bf16x8;

static __device__ __forceinline__ unsigned short f2bf(float f) {
  union { float f; unsigned u; } v; v.f = f;
  unsigned u = v.u;
  unsigned r = (u + 0x7FFFu + ((u >> 16) & 1u)) >> 16;   // RNE
  return (unsigned short)r;
}
static __device__ __forceinline__ unsigned short f2bf_cast(float f) {
  __bf16 h = (__bf16)f;                                   // HW cvt, RNE
  return __builtin_bit_cast(unsigned short, h);
}
// two packed bf16 pairs: out = bf16(relu(a+b)) lane-wise
static __device__ __forceinline__ unsigned addrelu2(unsigned a, unsigned b) {
  float alo = __builtin_bit_cast(float, a << 16);
  float ahi = __builtin_bit_cast(float, a & 0xffff0000u);
  float blo = __builtin_bit_cast(float, b << 16);
  float bhi = __builtin_bit_cast(float, b & 0xffff0000u);
  float slo = fmaxf(alo + blo, 0.f);
  float shi = fmaxf(ahi + bhi, 0.f);
  return (unsigned)f2bf_cast(slo) | ((unsigned)f2bf_cast(shi) << 16);
}

// ---------------------------------------------------------------------------
// Pack W0,W1 [512x512] into 32x32x16-bf16 fragment order:
//   off = ((wtile*32 + ks)*64 + lane)*8 + j, value = W[k][n]
// (W0p's ks 0..15 cover K rows 0..255 = W0a; ks 16..31 cover 256..511 = W0b.)
// W2 [512x5] padded N=16 into 16x16x32 fragment order.
// ws layout (ushort): [0,262144) W0p | [262144,524288) W1p | [524288,532480)
// W2p | [532480, +10240000) yab: per node 1024 = [ya(+b0) 0..511 | yb 512..1023]
// ---------------------------------------------------------------------------
__global__ __launch_bounds__(256) void pack_weights(
    const float* __restrict__ W0, const float* __restrict__ W1,
    const float* __restrict__ W2, unsigned short* __restrict__ wp) {
  int tid = blockIdx.x * 256 + threadIdx.x;
  if (tid < 2 * 262144) {
    int sel = tid >> 18;
    int t = tid & 262143;
    int n = t & 511, k = t >> 9;            // coalesced read along n
    const float* W = sel ? W1 : W0;
    float val = W[k * 512 + n];
    int ntile = n >> 5, ks = k >> 4;
    int lane = (((k >> 3) & 1) << 5) | (n & 31);
    int j = k & 7;
    int off = (((ntile * 32 + ks) * 64 + lane) << 3) | j;
    wp[sel * 262144 + off] = f2bf(val);
  } else {
    int t2 = tid - 524288;
    if (t2 < 8192) {                         // W2 padded N=5 -> 16
      int j = t2 & 7, lane = (t2 >> 3) & 63, k0 = t2 >> 9;
      int k = k0 * 32 + ((lane >> 4) << 3) + j;
      int n = lane & 15;
      float val = (n < OUTD) ? W2[k * OUTD + n] : 0.0f;
      wp[524288 + t2] = f2bf(val);
    }
  }
}

// ---------------------------------------------------------------------------
// Node-level layer-0 precompute: yab[node][0..512) = x[node]@W0a + b0,
// yab[node][512..1024) = x[node]@W0b.   5.2 GFLOP one-shot.
// Block = 32 nodes, 256 thr (4 waves). Wave w -> global ftiles 8w..8w+7
// (w<2: ya, bias C-init; w>=2: yb, zero C-init; W0p ksOff = (w>>1)*16).
// LDS x-tile [32 rows][256 cols] bf16 (16 KB, swizzle byte^=(row&7)<<4).
// ---------------------------------------------------------------------------
__global__ __launch_bounds__(256, 2) void node_mlp0(
    const float* __restrict__ x, const float* __restrict__ b0,
    const unsigned short* __restrict__ wp, unsigned short* __restrict__ yab) {
  __shared__ uint4 ldsv2[1024];               // 16384 B
  unsigned char* lds = (unsigned char*)ldsv2;
  const int tid = threadIdx.x;
  const int lane = tid & 63;
  const int w = tid >> 6;                     // wave 0..3
  const int l31 = lane & 31, h = lane >> 5;
  const int n0 = blockIdx.x * 32;

  // stage x[32][256] f32 -> bf16 LDS
  {
    const int r = tid >> 3, p = tid & 7;      // 8 thr/row
    int node = n0 + r; if (node > 9999) node = 9999;
    const float* s = x + (size_t)node * 256 + p * 32;
    const unsigned rowb = (unsigned)r * 512;
    const unsigned sx = (unsigned)((r & 7) << 4);
#pragma unroll
    for (int c = 0; c < 4; ++c) {
      const int kk = (c + p) & 3;
      const float4 f0 = *(const float4*)(s + kk * 8);
      const float4 f1 = *(const float4*)(s + kk * 8 + 4);
      uint4 pk;
      pk.x = (unsigned)f2bf(f0.x) | ((unsigned)f2bf(f0.y) << 16);
      pk.y = (unsigned)f2bf(f0.z) | ((unsigned)f2bf(f0.w) << 16);
      pk.z = (unsigned)f2bf(f1.x) | ((unsigned)f2bf(f1.y) << 16);
      pk.w = (unsigned)f2bf(f1.z) | ((unsigned)f2bf(f1.w) << 16);
      *(uint4*)(lds + rowb + (((unsigned)(p * 64 + kk * 16)) ^ sx)) = pk;
    }
  }
  __syncthreads();

  const unsigned sx31 = (unsigned)((l31 & 7) << 4);
  const int ntb = (w & 1) * 8;                // W0p ntile base for this wave
  const int ksOff = (w >> 1) * 16;            // 0 = W0a, 16 = W0b

  f32x16 acc[8];
#pragma unroll
  for (int f = 0; f < 8; ++f) {
    if (w < 2) {
      const int gf = w * 8 + f;
#pragma unroll
      for (int qd = 0; qd < 4; ++qd) {
        const float4 bq = *(const float4*)(b0 + gf * 32 + 8 * qd + 4 * h);
#pragma unroll
        for (int rr = 0; rr < 4; ++rr) acc[f][4 * qd + rr] = bq[rr];
      }
    } else {
#pragma unroll
      for (int i = 0; i < 16; ++i) acc[f][i] = 0.f;
    }
  }

#pragma unroll 2
  for (int ks = 0; ks < 16; ++ks) {
    const unsigned cb = (unsigned)(ks * 32 + h * 16);
    bf16x8 e0 = *(const bf16x8*)(lds + (unsigned)l31 * 512 + (cb ^ sx31));
#pragma unroll
    for (int f = 0; f < 8; ++f) {
      const bf16x8 wf = *(const bf16x8*)(wp +
          ((size_t)(((ntb + f) * 32) + ks + ksOff) * 64 + lane) * 8);
      acc[f] = __builtin_amdgcn_mfma_f32_32x32x16_bf16(wf, e0, acc[f], 0, 0, 0);
    }
  }

  // scatter to yab (L2 write-combines; one-shot kernel)
  {
    int node = n0 + l31; if (node > 9999) node = 9999;
    unsigned short* yrow = yab + (size_t)node * 1024;
#pragma unroll
    for (int f = 0; f < 8; ++f) {
      const int gf = w * 8 + f;               // global ftile 0..31
#pragma unroll
      for (int reg = 0; reg < 16; ++reg) {
        const int feat = gf * 32 + (reg & 3) + 8 * (reg >> 2) + 4 * h;
        yrow[feat] = f2bf_cast(acc[f][reg]);
      }
    }
  }
}

// ---------------------------------------------------------------------------
// Edge kernel, layer-0-factored: staging = gather ya[src]/yb[dst] + add +
// relu (no GEMM), then ONE hidden k-loop (L1) + epilogue + L2 + pair-mean.
// Skeleton = R18 (K-staggered, e-frag pipelined, no setprio).
// One block = 64 edges, 256 thr (4 waves), 2 blocks/CU; ~100 VGPR.
// ---------------------------------------------------------------------------
__global__ __launch_bounds__(256, 2) void edge_mlp2(
    const int* __restrict__ eidx, const float* __restrict__ b1,
    const float* __restrict__ b2, const unsigned short* __restrict__ wp,
    const unsigned short* __restrict__ yab, float* __restrict__ out) {
  __shared__ uint4 ldsv[4096 + 80];           // 65536 + 1280 B
  unsigned char* lds = (unsigned char*)ldsv;
  float* obuf = (float*)(lds + 65536);        // 64*5 f32

  const int tid = threadIdx.x;
  const int lane = tid & 63;
  const int w = tid >> 6;                     // wave 0..3
  const int l31 = lane & 31, h = lane >> 5;
  const int l15 = lane & 15, q = lane >> 4;
  const unsigned t = blockIdx.x;
  const int phase = ((int)t >> 3) & 31;       // per-XCD-position K stagger

  // ---- stage H0[64][512]: relu(ya[src] + yb[dst]) (b0 folded into ya) ----
  {
    const int r = tid >> 2, p = tid & 3;      // 4 thr/row, 128 feats each
    const int e = (int)t * 64 + r;
    const int src = eidx[e];
    const int dst = eidx[E_TOTAL + e];
    const unsigned short* pa = yab + (size_t)src * 1024 + p * 128;
    const unsigned short* pb = yab + (size_t)dst * 1024 + 512 + p * 128;
    const unsigned rowb = (unsigned)r * 1024;
    const unsigned sx = (unsigned)((r & 7) << 4);
    const unsigned cb0 = (unsigned)(p * 256);
#pragma unroll
    for (int i = 0; i < 16; ++i) {
      const int kk = (i + 4 * p) & 15;        // phase: spread LDS banks
      const uint4 a = *(const uint4*)(pa + kk * 8);
      const uint4 b = *(const uint4*)(pb + kk * 8);
      uint4 o;
      o.x = addrelu2(a.x, b.x);
      o.y = addrelu2(a.y, b.y);
      o.z = addrelu2(a.z, b.z);
      o.w = addrelu2(a.w, b.w);
      *(uint4*)(lds + rowb + ((cb0 + (unsigned)kk * 16) ^ sx)) = o;
    }
  }
  __syncthreads();

  const unsigned sx31 = (unsigned)((l31 & 7) << 4);
  const unsigned er0 = (unsigned)l31 * 1024;
  const unsigned er1 = (unsigned)(32 + l31) * 1024;

  // ===== hidden layer 1 (the only per-edge 512x512 GEMM left) =====
  {
    const unsigned short* wl = wp + 262144;   // W1p
    const unsigned short* wbA = wl + (size_t)(4 * w) * 16384 + (size_t)lane * 8;
    const unsigned short* wbB = wbA + 16384;
    const unsigned short* wbC = wbA + 32768;
    const unsigned short* wbD = wbA + 49152;

    f32x16 aA0, aA1, aB0, aB1, aC0, aC1, aD0, aD1;
#define BINIT(ACC0, ACC1, F)                                                   \
    {                                                                          \
      _Pragma("unroll")                                                        \
      for (int qd = 0; qd < 4; ++qd) {                                         \
        const float4 bq = *(const float4*)(b1 + w * 128 + (F) * 32 + 8 * qd + 4 * h); \
        _Pragma("unroll")                                                      \
        for (int rr = 0; rr < 4; ++rr) {                                       \
          (ACC0)[4 * qd + rr] = bq[rr];                                        \
          (ACC1)[4 * qd + rr] = bq[rr];                                        \
        }                                                                      \
      }                                                                        \
    }
    BINIT(aA0, aA1, 0) BINIT(aB0, aB1, 1) BINIT(aC0, aC1, 2) BINIT(aD0, aD1, 3)
#undef BINIT

    bf16x8 cwA = *(const bf16x8*)(wbA + phase * 512);
    bf16x8 cwB = *(const bf16x8*)(wbB + phase * 512);
    bf16x8 cwC = *(const bf16x8*)(wbC + phase * 512);
    bf16x8 cwD = *(const bf16x8*)(wbD + phase * 512);
    const unsigned cb00 = (unsigned)(phase * 32 + h * 16);
    bf16x8 e0 = *(const bf16x8*)(lds + er0 + (cb00 ^ sx31));
    bf16x8 e1 = *(const bf16x8*)(lds + er1 + (cb00 ^ sx31));

#pragma unroll 2
    for (int i = 0; i < 32; ++i) {
      const int ks = (i + phase) & 31;
      const int kp = (ks + 1) & 31;
      bf16x8 nwA = *(const bf16x8*)(wbA + kp * 512);
      bf16x8 nwB = *(const bf16x8*)(wbB + kp * 512);
      bf16x8 nwC = *(const bf16x8*)(wbC + kp * 512);
      bf16x8 nwD = *(const bf16x8*)(wbD + kp * 512);
      const unsigned cbn = (unsigned)(kp * 32 + h * 16);
      bf16x8 ne0 = *(const bf16x8*)(lds + er0 + (cbn ^ sx31));
      bf16x8 ne1 = *(const bf16x8*)(lds + er1 + (cbn ^ sx31));
      aA0 = __builtin_amdgcn_mfma_f32_32x32x16_bf16(cwA, e0, aA0, 0, 0, 0);
      aB0 = __builtin_amdgcn_mfma_f32_32x32x16_bf16(cwB, e0, aB0, 0, 0, 0);
      aC0 = __builtin_amdgcn_mfma_f32_32x32x16_bf16(cwC, e0, aC0, 0, 0, 0);
      aD0 = __builtin_amdgcn_mfma_f32_32x32x16_bf16(cwD, e0, aD0, 0, 0, 0);
      aA1 = __builtin_amdgcn_mfma_f32_32x32x16_bf16(cwA, e1, aA1, 0, 0, 0);
      aB1 = __builtin_amdgcn_mfma_f32_32x32x16_bf16(cwB, e1, aB1, 0, 0, 0);
      aC1 = __builtin_amdgcn_mfma_f32_32x32x16_bf16(cwC, e1, aC1, 0, 0, 0);
      aD1 = __builtin_amdgcn_mfma_f32_32x32x16_bf16(cwD, e1, aD1, 0, 0, 0);
      cwA = nwA; cwB = nwB; cwC = nwC; cwD = nwD;
      e0 = ne0; e1 = ne1;
    }

    __syncthreads();

    // relu + cvt + write H over A, b64 quads (C: col=edge, row=feature)
#define EPI_TILE(ACC, F, ET)                                                   \
    {                                                                          \
      const unsigned rowb = (unsigned)((ET) * 32 + l31) * 1024;                \
      const unsigned cbase = (unsigned)(256 * w + 64 * (F) + 8 * h);           \
      _Pragma("unroll")                                                        \
      for (int qd = 0; qd < 4; ++qd) {                                         \
        uint2 pk2;                                                             \
        pk2.x = (unsigned)f2bf_cast(fmaxf((ACC)[4 * qd + 0], 0.f)) |           \
                ((unsigned)f2bf_cast(fmaxf((ACC)[4 * qd + 1], 0.f)) << 16);    \
        pk2.y = (unsigned)f2bf_cast(fmaxf((ACC)[4 * qd + 2], 0.f)) |           \
                ((unsigned)f2bf_cast(fmaxf((ACC)[4 * qd + 3], 0.f)) << 16);    \
        *(uint2*)(lds + rowb + ((cbase + 16u * qd) ^ sx31)) = pk2;             \
      }                                                                        \
    }
    EPI_TILE(aA0, 0, 0) EPI_TILE(aA1, 0, 1)
    EPI_TILE(aB0, 1, 0) EPI_TILE(aB1, 1, 1)
    EPI_TILE(aC0, 2, 0) EPI_TILE(aC1, 2, 1)
    EPI_TILE(aD0, 3, 0) EPI_TILE(aD1, 3, 1)
#undef EPI_TILE
    __syncthreads();
  }

  // ===== layer 2 (swapped, staggered): wave w -> edges w*16..+15 =====
  {
    f32x4 acc2; acc2[0] = 0.f; acc2[1] = 0.f; acc2[2] = 0.f; acc2[3] = 0.f;
    const unsigned short* w2b = wp + 524288 + (size_t)lane * 8;
    const unsigned row = (unsigned)(w * 16 + l15);
    const unsigned rsx = (row & 7) << 4;
    const int ph16 = phase & 15;
#pragma unroll
    for (int i = 0; i < 16; ++i) {
      const int k0 = (i + ph16) & 15;
      bf16x8 eF = *(const bf16x8*)(lds + row * 1024 + (((unsigned)(k0 * 64 + q * 16)) ^ rsx));
      bf16x8 wF = *(const bf16x8*)(w2b + k0 * 512);
      acc2 = __builtin_amdgcn_mfma_f32_16x16x32_bf16(wF, eF, acc2, 0, 0, 0);
    }
    const int e = w * 16 + l15;
#pragma unroll
    for (int r = 0; r < 4; ++r) {
      const float s = __shfl_xor(acc2[r], 1);
      const float m = 0.5f * (acc2[r] + s);
      if (q == 0) {
        obuf[e * OUTD + r] = m + b2[r];
      } else if (q == 1 && r == 0) {
        obuf[e * OUTD + 4] = m + b2[4];
      }
    }
  }
  __syncthreads();

  // ===== coalesced out store (20 full 64B lines) =====
  {
    uint4* dst = (uint4*)(out + (size_t)t * 320);
    const uint4* sob = (const uint4*)obuf;
    if (tid < 80) dst[tid] = sob[tid];
  }
}

// ---------------------------------------------------------------------------
// Fallback (ws too small for yab): R14 full 3-layer kernel, sync f32 gather.
// ---------------------------------------------------------------------------
__global__ __launch_bounds__(256, 2) void edge_mlp_full(
    const float* __restrict__ x, const int* __restrict__ eidx,
    const float* __restrict__ b0, const float* __restrict__ b1,
    const float* __restrict__ b2, const unsigned short* __restrict__ wp,
    float* __restrict__ out) {
  __shared__ uint4 ldsv[4096 + 80];
  unsigned char* lds = (unsigned char*)ldsv;
  float* obuf = (float*)(lds + 65536);

  const int tid = threadIdx.x;
  const int lane = tid & 63;
  const int w = tid >> 6;
  const int l31 = lane & 31, h = lane >> 5;
  const int l15 = lane & 15, q = lane >> 4;
  const unsigned t = blockIdx.x;
  const int phase = ((int)t >> 3) & 31;

  {
    const int p = tid & 7;
#pragma unroll
    for (int pass = 0; pass < 2; ++pass) {
      const int r = (tid >> 3) + 32 * pass;
      const int e = (int)t * 64 + r;
      const int node = eidx[(p >> 2) * E_TOTAL + e];
      const unsigned rowb = (unsigned)r * 1024;
      const unsigned sx = (unsigned)((r & 7) << 4);
      const unsigned cb0 = (unsigned)((p >> 2) * 512 + (p & 3) * 128);
      const float* s = x + (size_t)node * 256 + (p & 3) * 64;
#pragma unroll
      for (int jj = 0; jj < 8; ++jj) {
        const int kk = (jj + p) & 7;
        const float4 f0 = *(const float4*)(s + kk * 8);
        const float4 f1 = *(const float4*)(s + kk * 8 + 4);
        uint4 pk;
        pk.x = (unsigned)f2bf(f0.x) | ((unsigned)f2bf(f0.y) << 16);
        pk.y = (unsigned)f2bf(f0.z) | ((unsigned)f2bf(f0.w) << 16);
        pk.z = (unsigned)f2bf(f1.x) | ((unsigned)f2bf(f1.y) << 16);
        pk.w = (unsigned)f2bf(f1.z) | ((unsigned)f2bf(f1.w) << 16);
        *(uint4*)(lds + rowb + ((cb0 + (unsigned)kk * 16) ^ sx)) = pk;
      }
    }
  }
  __syncthreads();

  const unsigned sx31 = (unsigned)((l31 & 7) << 4);

#pragma unroll 1
  for (int L = 0; L < 2; ++L) {
    const unsigned short* wl = wp + L * 262144;
    const unsigned short* wbA = wl + (size_t)(4 * w) * 16384 + (size_t)lane * 8;
    const unsigned short* wbB = wbA + 16384;
    const unsigned short* wbC = wbA + 32768;
    const unsigned short* wbD = wbA + 49152;
    const float* bias = L ? b1 : b0;

    f32x16 aA0, aA1, aB0, aB1, aC0, aC1, aD0, aD1;
#define BINIT(ACC0, ACC1, F)                                                   \
    {                                                                          \
      _Pragma("unroll")                                                        \
      for (int qd = 0; qd < 4; ++qd) {                                         \
        const float4 bq = *(const float4*)(bias + w * 128 + (F) * 32 + 8 * qd + 4 * h); \
        _Pragma("unroll")                                                      \
        for (int rr = 0; rr < 4; ++rr) {                                       \
          (ACC0)[4 * qd + rr] = bq[rr];                                        \
          (ACC1)[4 * qd + rr] = bq[rr];                                        \
        }                                                                      \
      }                                                                        \
    }
    BINIT(aA0, aA1, 0) BINIT(aB0, aB1, 1) BINIT(aC0, aC1, 2) BINIT(aD0, aD1, 3)
#undef BINIT

    bf16x8 cwA = *(const bf16x8*)(wbA + phase * 512);
    bf16x8 cwB = *(const bf16x8*)(wbB + phase * 512);
    bf16x8 cwC = *(const bf16x8*)(wbC + phase * 512);
    bf16x8 cwD = *(const bf16x8*)(wbD + phase * 512);

#pragma unroll 2
    for (int i = 0; i < 32; ++i) {
      const int ks = (i + phase) & 31;
      const int kp = (ks + 1) & 31;
      bf16x8 nwA = *(const bf16x8*)(wbA + kp * 512);
      bf16x8 nwB = *(const bf16x8*)(wbB + kp * 512);
      bf16x8 nwC = *(const bf16x8*)(wbC + kp * 512);
      bf16x8 nwD = *(const bf16x8*)(wbD + kp * 512);
      const unsigned cb = (unsigned)(ks * 32 + h * 16);
      bf16x8 e0 = *(const bf16x8*)(lds + (unsigned)l31 * 1024 + (cb ^ sx31));
      bf16x8 e1 = *(const bf16x8*)(lds + (unsigned)(32 + l31) * 1024 + (cb ^ sx31));
      aA0 = __builtin_amdgcn_mfma_f32_32x32x16_bf16(cwA, e0, aA0, 0, 0, 0);
      aB0 = __builtin_amdgcn_mfma_f32_32x32x16_bf16(cwB, e0, aB0, 0, 0, 0);
      aC0 = __builtin_amdgcn_mfma_f32_32x32x16_bf16(cwC, e0, aC0, 0, 0, 0);
      aD0 = __builtin_amdgcn_mfma_f32_32x32x16_bf16(cwD, e0, aD0, 0, 0, 0);
      aA1 = __builtin_amdgcn_mfma_f32_32x32x16_bf16(cwA, e1, aA1, 0, 0, 0);
      aB1 = __builtin_amdgcn_mfma_f32_32x32x16_bf16(cwB, e1, aB1, 0, 0, 0);
      aC1 = __builtin_amdgcn_mfma_f32_32x32x16_bf16(cwC, e1, aC1, 0, 0, 0);
      aD1 = __builtin_amdgcn_mfma_f32_32x32x16_bf16(cwD, e1, aD1, 0, 0, 0);
      cwA = nwA; cwB = nwB; cwC = nwC; cwD = nwD;
    }

    __syncthreads();
#define EPI_TILE(ACC, F, ET)                                                   \
    {                                                                          \
      const unsigned rowb = (unsigned)((ET) * 32 + l31) * 1024;                \
      const unsigned cbase = (unsigned)(256 * w + 64 * (F) + 8 * h);           \
      _Pragma("unroll")                                                        \
      for (int qd = 0; qd < 4; ++qd) {                                         \
        uint2 pk2;                                                             \
        pk2.x = (unsigned)f2bf_cast(fmaxf((ACC)[4 * qd + 0], 0.f)) |           \
                ((unsigned)f2bf_cast(fmaxf((ACC)[4 * qd + 1], 0.f)) << 16);    \
        pk2.y = (unsigned)f2bf_cast(fmaxf((ACC)[4 * qd + 2], 0.f)) |           \
                ((unsigned)f2bf_cast(fmaxf((ACC)[4 * qd + 3], 0.f)) << 16);    \
        *(uint2*)(lds + rowb + ((cbase + 16u * qd) ^ sx31)) = pk2;             \
      }                                                                        \
    }
    EPI_TILE(aA0, 0, 0) EPI_TILE(aA1, 0, 1)
    EPI_TILE(aB0, 1, 0) EPI_TILE(aB1, 1, 1)
    EPI_TILE(aC0, 2, 0) EPI_TILE(aC1, 2, 1)
    EPI_TILE(aD0, 3, 0) EPI_TILE(aD1, 3, 1)
#undef EPI_TILE
    __syncthreads();
  }

  {
    f32x4 acc2; acc2[0] = 0.f; acc2[1] = 0.f; acc2[2] = 0.f; acc2[3] = 0.f;
    const unsigned short* w2b = wp + 524288 + (size_t)lane * 8;
    const unsigned row = (unsigned)(w * 16 + l15);
    const unsigned rsx = (row & 7) << 4;
    const int ph16 = phase & 15;
#pragma unroll
    for (int i = 0; i < 16; ++i) {
      const int k0 = (i + ph16) & 15;
      bf16x8 eF = *(const bf16x8*)(lds + row * 1024 + (((unsigned)(k0 * 64 + q * 16)) ^ rsx));
      bf16x8 wF = *(const bf16x8*)(w2b + k0 * 512);
      acc2 = __builtin_amdgcn_mfma_f32_16x16x32_bf16(wF, eF, acc2, 0, 0, 0);
    }
    const int e = w * 16 + l15;
#pragma unroll
    for (int r = 0; r < 4; ++r) {
      const float s = __shfl_xor(acc2[r], 1);
      const float m = 0.5f * (acc2[r] + s);
      if (q == 0) {
        obuf[e * OUTD + r] = m + b2[r];
      } else if (q == 1 && r == 0) {
        obuf[e * OUTD + 4] = m + b2[4];
      }
    }
  }
  __syncthreads();
  {
    uint4* dst = (uint4*)(out + (size_t)t * 320);
    const uint4* sob = (const uint4*)obuf;
    if (tid < 80) dst[tid] = sob[tid];
  }
}

extern "C" void kernel_launch(void* const* d_in, const int* in_sizes, int n_in,
                              void* d_out, int out_size, void* d_ws, size_t ws_size,
                              hipStream_t stream) {
  const float* x  = (const float*)d_in[0];
  const int* eidx = (const int*)d_in[1];
  const float* W0 = (const float*)d_in[2];
  const float* b0 = (const float*)d_in[3];
  const float* W1 = (const float*)d_in[4];
  const float* b1 = (const float*)d_in[5];
  const float* W2 = (const float*)d_in[6];
  const float* b2 = (const float*)d_in[7];
  float* out = (float*)d_out;
  unsigned short* wp = (unsigned short*)d_ws;
  if (ws_size < (size_t)WP_USHORTS * 2) return;

  pack_weights<<<2080, 256, 0, stream>>>(W0, W1, W2, wp);
  if (ws_size >= WS_NEED) {
    unsigned short* yab = wp + WP_USHORTS;
    node_mlp0<<<313, 256, 0, stream>>>(x, b0, wp, yab);
    edge_mlp2<<<NTILES, 256, 0, stream>>>(eidx, b1, b2, wp, yab, out);
  } else {
    edge_mlp_full<<<NTILES, 256, 0, stream>>>(x, eidx, b0, b1, b2, wp, out);
  }
}

// Round 20
// 226.409 us; speedup vs baseline: 1.2684x; 1.0126x over previous
//
#include <hip/hip_runtime.h>

#define E_TOTAL 200000
#define NPAIR 100000
#define N_NODES 10000
#define OUTD 5
#define NTILES 3125           // 200000 / 64 exactly
#define WP_USHORTS 532480     // W0p (262144) + W1p (262144) + W2p (8192)
#define YAB_USHORTS 10240000  // 10000 nodes x 1024 (ya|yb) bf16
#define WS_Y ((size_t)(WP_USHORTS + YAB_USHORTS) * 2)
// sort extras (bytes, after yab): hist u32[10240] | perm u32[200000] |
// rank u32[200000] | outp f32[1000000]
#define WS_SORT (WS_Y + 40960 + 800000 + 800000 + 4000000)

typedef __attribute__((ext_vector_type(4))) float f32x4;
typedef __attribute__((ext_vector_type(16))) float f32x16;
typedef __attribute__((ext_vector_type(8))) __bf16 bf16x8;

static __device__ __forceinline__ unsigned short f2bf(float f) {
  union { float f; unsigned u; } v; v.f = f;
  unsigned u = v.u;
  unsigned r = (u + 0x7FFFu + ((u >> 16) & 1u)) >> 16;   // RNE
  return (unsigned short)r;
}
static __device__ __forceinline__ unsigned short f2bf_cast(float f) {
  __bf16 h = (__bf16)f;                                   // HW cvt, RNE
  return __builtin_bit_cast(unsigned short, h);
}
static __device__ __forceinline__ unsigned addrelu2(unsigned a, unsigned b) {
  float alo = __builtin_bit_cast(float, a << 16);
  float ahi = __builtin_bit_cast(float, a & 0xffff0000u);
  float blo = __builtin_bit_cast(float, b << 16);
  float bhi = __builtin_bit_cast(float, b & 0xffff0000u);
  float slo = fmaxf(alo + blo, 0.f);
  float shi = fmaxf(ahi + bhi, 0.f);
  return (unsigned)f2bf_cast(slo) | ((unsigned)f2bf_cast(shi) << 16);
}

// ---------------------------------------------------------------------------
// Pack W0,W1 [512x512] into 32x32x16-bf16 fragment order; W2 padded N=16.
// ---------------------------------------------------------------------------
__global__ __launch_bounds__(256) void pack_weights(
    const float* __restrict__ W0, const float* __restrict__ W1,
    const float* __restrict__ W2, unsigned short* __restrict__ wp) {
  int tid = blockIdx.x * 256 + threadIdx.x;
  if (tid < 2 * 262144) {
    int sel = tid >> 18;
    int t = tid & 262143;
    int n = t & 511, k = t >> 9;
    const float* W = sel ? W1 : W0;
    float val = W[k * 512 + n];
    int ntile = n >> 5, ks = k >> 4;
    int lane = (((k >> 3) & 1) << 5) | (n & 31);
    int j = k & 7;
    int off = (((ntile * 32 + ks) * 64 + lane) << 3) | j;
    wp[sel * 262144 + off] = f2bf(val);
  } else {
    int t2 = tid - 524288;
    if (t2 < 8192) {
      int j = t2 & 7, lane = (t2 >> 3) & 63, k0 = t2 >> 9;
      int k = k0 * 32 + ((lane >> 4) << 3) + j;
      int n = lane & 15;
      float val = (n < OUTD) ? W2[k * OUTD + n] : 0.0f;
      wp[524288 + t2] = f2bf(val);
    }
  }
}

// ---------------------------------------------------------------------------
// Node-level layer-0 precompute (identical to R19; 5.2 GFLOP one-shot).
// ---------------------------------------------------------------------------
__global__ __launch_bounds__(256, 2) void node_mlp0(
    const float* __restrict__ x, const float* __restrict__ b0,
    const unsigned short* __restrict__ wp, unsigned short* __restrict__ yab) {
  __shared__ uint4 ldsv2[1024];               // 16384 B
  unsigned char* lds = (unsigned char*)ldsv2;
  const int tid = threadIdx.x;
  const int lane = tid & 63;
  const int w = tid >> 6;
  const int l31 = lane & 31, h = lane >> 5;
  const int n0 = blockIdx.x * 32;

  {
    const int r = tid >> 3, p = tid & 7;
    int node = n0 + r; if (node > N_NODES - 1) node = N_NODES - 1;
    const float* s = x + (size_t)node * 256 + p * 32;
    const unsigned rowb = (unsigned)r * 512;
    const unsigned sx = (unsigned)((r & 7) << 4);
#pragma unroll
    for (int c = 0; c < 4; ++c) {
      const int kk = (c + p) & 3;
      const float4 f0 = *(const float4*)(s + kk * 8);
      const float4 f1 = *(const float4*)(s + kk * 8 + 4);
      uint4 pk;
      pk.x = (unsigned)f2bf(f0.x) | ((unsigned)f2bf(f0.y) << 16);
      pk.y = (unsigned)f2bf(f0.z) | ((unsigned)f2bf(f0.w) << 16);
      pk.z = (unsigned)f2bf(f1.x) | ((unsigned)f2bf(f1.y) << 16);
      pk.w = (unsigned)f2bf(f1.z) | ((unsigned)f2bf(f1.w) << 16);
      *(uint4*)(lds + rowb + (((unsigned)(p * 64 + kk * 16)) ^ sx)) = pk;
    }
  }
  __syncthreads();

  const unsigned sx31 = (unsigned)((l31 & 7) << 4);
  const int ntb = (w & 1) * 8;
  const int ksOff = (w >> 1) * 16;

  f32x16 acc[8];
#pragma unroll
  for (int f = 0; f < 8; ++f) {
    if (w < 2) {
      const int gf = w * 8 + f;
#pragma unroll
      for (int qd = 0; qd < 4; ++qd) {
        const float4 bq = *(const float4*)(b0 + gf * 32 + 8 * qd + 4 * h);
#pragma unroll
        for (int rr = 0; rr < 4; ++rr) acc[f][4 * qd + rr] = bq[rr];
      }
    } else {
#pragma unroll
      for (int i = 0; i < 16; ++i) acc[f][i] = 0.f;
    }
  }

#pragma unroll 2
  for (int ks = 0; ks < 16; ++ks) {
    const unsigned cb = (unsigned)(ks * 32 + h * 16);
    bf16x8 e0 = *(const bf16x8*)(lds + (unsigned)l31 * 512 + (cb ^ sx31));
#pragma unroll
    for (int f = 0; f < 8; ++f) {
      const bf16x8 wf = *(const bf16x8*)(wp +
          ((size_t)(((ntb + f) * 32) + ks + ksOff) * 64 + lane) * 8);
      acc[f] = __builtin_amdgcn_mfma_f32_32x32x16_bf16(wf, e0, acc[f], 0, 0, 0);
    }
  }

  {
    int node = n0 + l31; if (node > N_NODES - 1) node = N_NODES - 1;
    unsigned short* yrow = yab + (size_t)node * 1024;
#pragma unroll
    for (int f = 0; f < 8; ++f) {
      const int gf = w * 8 + f;
#pragma unroll
      for (int reg = 0; reg < 16; ++reg) {
        const int feat = gf * 32 + (reg & 3) + 8 * (reg >> 2) + 4 * h;
        yrow[feat] = f2bf_cast(acc[f][reg]);
      }
    }
  }
}

// ===== counting-sort edges by src node ======================================
__global__ __launch_bounds__(256) void zero_hist(unsigned* __restrict__ hist) {
  int i = blockIdx.x * 256 + threadIdx.x;
  if (i < 10240) hist[i] = 0u;
}
__global__ __launch_bounds__(256) void hist_src(
    const int* __restrict__ eidx, unsigned* __restrict__ hist) {
  int e = blockIdx.x * 256 + threadIdx.x;
  if (e < E_TOTAL) atomicAdd(&hist[eidx[e]], 1u);
}
__global__ __launch_bounds__(1024) void scan_hist(unsigned* __restrict__ hist) {
  __shared__ unsigned part[1024];
  const int t = threadIdx.x;
  unsigned loc[10];
  unsigned s = 0;
#pragma unroll
  for (int i = 0; i < 10; ++i) {
    const int idx = t * 10 + i;
    unsigned v = (idx < N_NODES) ? hist[idx] : 0u;
    loc[i] = v; s += v;
  }
  part[t] = s;
  __syncthreads();
  for (int off = 1; off < 1024; off <<= 1) {
    unsigned v = (t >= off) ? part[t - off] : 0u;
    __syncthreads();
    part[t] += v;
    __syncthreads();
  }
  unsigned run = (t == 0) ? 0u : part[t - 1];
#pragma unroll
  for (int i = 0; i < 10; ++i) {
    const int idx = t * 10 + i;
    if (idx < N_NODES) { hist[idx] = run; run += loc[i]; }
  }
}
__global__ __launch_bounds__(256) void scatter_perm(
    const int* __restrict__ eidx, unsigned* __restrict__ hist,
    unsigned* __restrict__ perm, unsigned* __restrict__ rank) {
  int e = blockIdx.x * 256 + threadIdx.x;
  if (e < E_TOTAL) {
    unsigned pos = atomicAdd(&hist[eidx[e]], 1u);
    perm[pos] = (unsigned)e;
    rank[e] = pos;
  }
}

// ---------------------------------------------------------------------------
// Edge kernel (layer-0 factored). SORTED=1: slots are src-sorted (perm), raw
// per-edge output to outp[slot] (contiguous). SORTED=0: R19 behavior (slot=e,
// pair-mean in-kernel, writes out). Skeleton: K-staggered, e-frag pipelined.
// ---------------------------------------------------------------------------
template <int SORTED>
__global__ __launch_bounds__(256, 2) void edge_mlp2(
    const int* __restrict__ eidx, const unsigned* __restrict__ perm,
    const float* __restrict__ b1, const float* __restrict__ b2,
    const unsigned short* __restrict__ wp,
    const unsigned short* __restrict__ yab, float* __restrict__ dst5) {
  __shared__ uint4 ldsv[4096 + 80];           // 65536 + 1280 B
  unsigned char* lds = (unsigned char*)ldsv;
  float* obuf = (float*)(lds + 65536);        // 64*5 f32

  const int tid = threadIdx.x;
  const int lane = tid & 63;
  const int w = tid >> 6;
  const int l31 = lane & 31, h = lane >> 5;
  const int l15 = lane & 15, q = lane >> 4;
  const unsigned t = blockIdx.x;
  const int phase = ((int)t >> 3) & 31;

  // ---- stage H0[64][512]: relu(ya[src] + yb[dst]) ----
  {
    const int r = tid >> 2, p = tid & 3;
    const int s = (int)t * 64 + r;
    const int e = SORTED ? (int)perm[s] : s;
    const int src = eidx[e];
    const int dst = eidx[E_TOTAL + e];
    const unsigned short* pa = yab + (size_t)src * 1024 + p * 128;
    const unsigned short* pb = yab + (size_t)dst * 1024 + 512 + p * 128;
    const unsigned rowb = (unsigned)r * 1024;
    const unsigned sx = (unsigned)((r & 7) << 4);
    const unsigned cb0 = (unsigned)(p * 256);
#pragma unroll
    for (int i = 0; i < 16; ++i) {
      const int kk = (i + 4 * p) & 15;
      const uint4 a = *(const uint4*)(pa + kk * 8);
      const uint4 b = *(const uint4*)(pb + kk * 8);
      uint4 o;
      o.x = addrelu2(a.x, b.x);
      o.y = addrelu2(a.y, b.y);
      o.z = addrelu2(a.z, b.z);
      o.w = addrelu2(a.w, b.w);
      *(uint4*)(lds + rowb + ((cb0 + (unsigned)kk * 16) ^ sx)) = o;
    }
  }
  __syncthreads();

  const unsigned sx31 = (unsigned)((l31 & 7) << 4);
  const unsigned er0 = (unsigned)l31 * 1024;
  const unsigned er1 = (unsigned)(32 + l31) * 1024;

  // ===== hidden layer 1 =====
  {
    const unsigned short* wl = wp + 262144;   // W1p
    const unsigned short* wbA = wl + (size_t)(4 * w) * 16384 + (size_t)lane * 8;
    const unsigned short* wbB = wbA + 16384;
    const unsigned short* wbC = wbA + 32768;
    const unsigned short* wbD = wbA + 49152;

    f32x16 aA0, aA1, aB0, aB1, aC0, aC1, aD0, aD1;
#define BINIT(ACC0, ACC1, F)                                                   \
    {                                                                          \
      _Pragma("unroll")                                                        \
      for (int qd = 0; qd < 4; ++qd) {                                         \
        const float4 bq = *(const float4*)(b1 + w * 128 + (F) * 32 + 8 * qd + 4 * h); \
        _Pragma("unroll")                                                      \
        for (int rr = 0; rr < 4; ++rr) {                                       \
          (ACC0)[4 * qd + rr] = bq[rr];                                        \
          (ACC1)[4 * qd + rr] = bq[rr];                                        \
        }                                                                      \
      }                                                                        \
    }
    BINIT(aA0, aA1, 0) BINIT(aB0, aB1, 1) BINIT(aC0, aC1, 2) BINIT(aD0, aD1, 3)
#undef BINIT

    bf16x8 cwA = *(const bf16x8*)(wbA + phase * 512);
    bf16x8 cwB = *(const bf16x8*)(wbB + phase * 512);
    bf16x8 cwC = *(const bf16x8*)(wbC + phase * 512);
    bf16x8 cwD = *(const bf16x8*)(wbD + phase * 512);
    const unsigned cb00 = (unsigned)(phase * 32 + h * 16);
    bf16x8 e0 = *(const bf16x8*)(lds + er0 + (cb00 ^ sx31));
    bf16x8 e1 = *(const bf16x8*)(lds + er1 + (cb00 ^ sx31));

#pragma unroll 2
    for (int i = 0; i < 32; ++i) {
      const int ks = (i + phase) & 31;
      const int kp = (ks + 1) & 31;
      bf16x8 nwA = *(const bf16x8*)(wbA + kp * 512);
      bf16x8 nwB = *(const bf16x8*)(wbB + kp * 512);
      bf16x8 nwC = *(const bf16x8*)(wbC + kp * 512);
      bf16x8 nwD = *(const bf16x8*)(wbD + kp * 512);
      const unsigned cbn = (unsigned)(kp * 32 + h * 16);
      bf16x8 ne0 = *(const bf16x8*)(lds + er0 + (cbn ^ sx31));
      bf16x8 ne1 = *(const bf16x8*)(lds + er1 + (cbn ^ sx31));
      aA0 = __builtin_amdgcn_mfma_f32_32x32x16_bf16(cwA, e0, aA0, 0, 0, 0);
      aB0 = __builtin_amdgcn_mfma_f32_32x32x16_bf16(cwB, e0, aB0, 0, 0, 0);
      aC0 = __builtin_amdgcn_mfma_f32_32x32x16_bf16(cwC, e0, aC0, 0, 0, 0);
      aD0 = __builtin_amdgcn_mfma_f32_32x32x16_bf16(cwD, e0, aD0, 0, 0, 0);
      aA1 = __builtin_amdgcn_mfma_f32_32x32x16_bf16(cwA, e1, aA1, 0, 0, 0);
      aB1 = __builtin_amdgcn_mfma_f32_32x32x16_bf16(cwB, e1, aB1, 0, 0, 0);
      aC1 = __builtin_amdgcn_mfma_f32_32x32x16_bf16(cwC, e1, aC1, 0, 0, 0);
      aD1 = __builtin_amdgcn_mfma_f32_32x32x16_bf16(cwD, e1, aD1, 0, 0, 0);
      cwA = nwA; cwB = nwB; cwC = nwC; cwD = nwD;
      e0 = ne0; e1 = ne1;
    }

    __syncthreads();

#define EPI_TILE(ACC, F, ET)                                                   \
    {                                                                          \
      const unsigned rowb = (unsigned)((ET) * 32 + l31) * 1024;                \
      const unsigned cbase = (unsigned)(256 * w + 64 * (F) + 8 * h);           \
      _Pragma("unroll")                                                        \
      for (int qd = 0; qd < 4; ++qd) {                                         \
        uint2 pk2;                                                             \
        pk2.x = (unsigned)f2bf_cast(fmaxf((ACC)[4 * qd + 0], 0.f)) |           \
                ((unsigned)f2bf_cast(fmaxf((ACC)[4 * qd + 1], 0.f)) << 16);    \
        pk2.y = (unsigned)f2bf_cast(fmaxf((ACC)[4 * qd + 2], 0.f)) |           \
                ((unsigned)f2bf_cast(fmaxf((ACC)[4 * qd + 3], 0.f)) << 16);    \
        *(uint2*)(lds + rowb + ((cbase + 16u * qd) ^ sx31)) = pk2;             \
      }                                                                        \
    }
    EPI_TILE(aA0, 0, 0) EPI_TILE(aA1, 0, 1)
    EPI_TILE(aB0, 1, 0) EPI_TILE(aB1, 1, 1)
    EPI_TILE(aC0, 2, 0) EPI_TILE(aC1, 2, 1)
    EPI_TILE(aD0, 3, 0) EPI_TILE(aD1, 3, 1)
#undef EPI_TILE
    __syncthreads();
  }

  // ===== layer 2: wave w -> slots w*16..+15 =====
  {
    f32x4 acc2; acc2[0] = 0.f; acc2[1] = 0.f; acc2[2] = 0.f; acc2[3] = 0.f;
    const unsigned short* w2b = wp + 524288 + (size_t)lane * 8;
    const unsigned row = (unsigned)(w * 16 + l15);
    const unsigned rsx = (row & 7) << 4;
    const int ph16 = phase & 15;
#pragma unroll
    for (int i = 0; i < 16; ++i) {
      const int k0 = (i + ph16) & 15;
      bf16x8 eF = *(const bf16x8*)(lds + row * 1024 + (((unsigned)(k0 * 64 + q * 16)) ^ rsx));
      bf16x8 wF = *(const bf16x8*)(w2b + k0 * 512);
      acc2 = __builtin_amdgcn_mfma_f32_16x16x32_bf16(wF, eF, acc2, 0, 0, 0);
    }
    const int e = w * 16 + l15;                // block-local slot
    if (SORTED) {
      // raw per-edge output (+bias); mean done by mean_pairs
#pragma unroll
      for (int r = 0; r < 4; ++r) {
        if (q == 0) obuf[e * OUTD + r] = acc2[r] + b2[r];
        else if (q == 1 && r == 0) obuf[e * OUTD + 4] = acc2[0] + b2[4];
      }
    } else {
#pragma unroll
      for (int r = 0; r < 4; ++r) {
        const float s = __shfl_xor(acc2[r], 1);
        const float m = 0.5f * (acc2[r] + s);
        if (q == 0) obuf[e * OUTD + r] = m + b2[r];
        else if (q == 1 && r == 0) obuf[e * OUTD + 4] = m + b2[4];
      }
    }
  }
  __syncthreads();

  // ===== coalesced store (20 full 64B lines) to outp (SORTED) or out =====
  {
    uint4* dst = (uint4*)(dst5 + (size_t)t * 320);
    const uint4* sob = (const uint4*)obuf;
    if (tid < 80) dst[tid] = sob[tid];
  }
}

// pair-mean epilogue: out[2m] = out[2m+1] = 0.5*(outp[rank[2m]]+outp[rank[2m+1]])
__global__ __launch_bounds__(256) void mean_pairs(
    const unsigned* __restrict__ rank, const float* __restrict__ outp,
    float* __restrict__ out) {
  int m = blockIdx.x * 256 + threadIdx.x;
  if (m < NPAIR) {
    const float* p0 = outp + (size_t)rank[2 * m] * OUTD;
    const float* p1 = outp + (size_t)rank[2 * m + 1] * OUTD;
    float v[OUTD];
#pragma unroll
    for (int i = 0; i < OUTD; ++i) v[i] = 0.5f * (p0[i] + p1[i]);
    float* o = out + (size_t)m * 2 * OUTD;
#pragma unroll
    for (int i = 0; i < OUTD; ++i) { o[i] = v[i]; o[OUTD + i] = v[i]; }
  }
}

extern "C" void kernel_launch(void* const* d_in, const int* in_sizes, int n_in,
                              void* d_out, int out_size, void* d_ws, size_t ws_size,
                              hipStream_t stream) {
  const float* x  = (const float*)d_in[0];
  const int* eidx = (const int*)d_in[1];
  const float* W0 = (const float*)d_in[2];
  const float* b0 = (const float*)d_in[3];
  const float* W1 = (const float*)d_in[4];
  const float* b1 = (const float*)d_in[5];
  const float* W2 = (const float*)d_in[6];
  const float* b2 = (const float*)d_in[7];
  float* out = (float*)d_out;
  unsigned short* wp = (unsigned short*)d_ws;
  if (ws_size < WS_Y) return;                 // need yab workspace

  pack_weights<<<2080, 256, 0, stream>>>(W0, W1, W2, wp);
  unsigned short* yab = wp + WP_USHORTS;
  node_mlp0<<<313, 256, 0, stream>>>(x, b0, wp, yab);

  if (ws_size >= WS_SORT) {
    unsigned char* base = (unsigned char*)d_ws + WS_Y;
    unsigned* hist = (unsigned*)base;                     // 10240 u32
    unsigned* perm = (unsigned*)(base + 40960);           // 200000 u32
    unsigned* rank = (unsigned*)(base + 40960 + 800000);  // 200000 u32
    float* outp = (float*)(base + 40960 + 1600000);       // 1e6 f32

    zero_hist<<<40, 256, 0, stream>>>(hist);
    hist_src<<<782, 256, 0, stream>>>(eidx, hist);
    scan_hist<<<1, 1024, 0, stream>>>(hist);
    scatter_perm<<<782, 256, 0, stream>>>(eidx, hist, perm, rank);
    edge_mlp2<1><<<NTILES, 256, 0, stream>>>(eidx, perm, b1, b2, wp, yab, outp);
    mean_pairs<<<391, 256, 0, stream>>>(rank, outp, out);
  } else {
    edge_mlp2<0><<<NTILES, 256, 0, stream>>>(eidx, nullptr, b1, b2, wp, yab, out);
  }
}

// Round 21
// 219.193 us; speedup vs baseline: 1.3102x; 1.0329x over previous
//
#include <hip/hip_runtime.h>

#define E_TOTAL 200000
#define NPAIR 100000
#define N_NODES 10000
#define OUTD 5
#define NTILES 3125           // 200000 / 64 exactly
#define WP_USHORTS 532480     // W0p (262144) + W1p (262144) + W2p (8192)
#define YAB_USHORTS 10240000  // 10000 nodes x 1024 (ya|yb) bf16
#define WS_Y ((size_t)(WP_USHORTS + YAB_USHORTS) * 2)
// sort extras (bytes, after yab): hist u32[10240] | perm u32[200000] |
// rank u32[200000] | outp f32[1000000]
#define WS_SORT (WS_Y + 40960 + 800000 + 800000 + 4000000)

typedef __attribute__((ext_vector_type(4))) float f32x4;
typedef __attribute__((ext_vector_type(16))) float f32x16;
typedef __attribute__((ext_vector_type(8))) __bf16 bf16x8;

static __device__ __forceinline__ unsigned short f2bf(float f) {
  union { float f; unsigned u; } v; v.f = f;
  unsigned u = v.u;
  unsigned r = (u + 0x7FFFu + ((u >> 16) & 1u)) >> 16;   // RNE
  return (unsigned short)r;
}
static __device__ __forceinline__ unsigned short f2bf_cast(float f) {
  __bf16 h = (__bf16)f;                                   // HW cvt, RNE
  return __builtin_bit_cast(unsigned short, h);
}
static __device__ __forceinline__ unsigned addrelu2(unsigned a, unsigned b) {
  float alo = __builtin_bit_cast(float, a << 16);
  float ahi = __builtin_bit_cast(float, a & 0xffff0000u);
  float blo = __builtin_bit_cast(float, b << 16);
  float bhi = __builtin_bit_cast(float, b & 0xffff0000u);
  float slo = fmaxf(alo + blo, 0.f);
  float shi = fmaxf(ahi + bhi, 0.f);
  return (unsigned)f2bf_cast(slo) | ((unsigned)f2bf_cast(shi) << 16);
}

// ---------------------------------------------------------------------------
// Pack W0,W1 [512x512] into 32x32x16-bf16 fragment order; W2 padded N=16.
// ---------------------------------------------------------------------------
__global__ __launch_bounds__(256) void pack_weights(
    const float* __restrict__ W0, const float* __restrict__ W1,
    const float* __restrict__ W2, unsigned short* __restrict__ wp) {
  int tid = blockIdx.x * 256 + threadIdx.x;
  if (tid < 2 * 262144) {
    int sel = tid >> 18;
    int t = tid & 262143;
    int n = t & 511, k = t >> 9;
    const float* W = sel ? W1 : W0;
    float val = W[k * 512 + n];
    int ntile = n >> 5, ks = k >> 4;
    int lane = (((k >> 3) & 1) << 5) | (n & 31);
    int j = k & 7;
    int off = (((ntile * 32 + ks) * 64 + lane) << 3) | j;
    wp[sel * 262144 + off] = f2bf(val);
  } else {
    int t2 = tid - 524288;
    if (t2 < 8192) {
      int j = t2 & 7, lane = (t2 >> 3) & 63, k0 = t2 >> 9;
      int k = k0 * 32 + ((lane >> 4) << 3) + j;
      int n = lane & 15;
      float val = (n < OUTD) ? W2[k * OUTD + n] : 0.0f;
      wp[524288 + t2] = f2bf(val);
    }
  }
}

// ---------------------------------------------------------------------------
// Node-level layer-0 precompute (identical to R19/R20; 5.2 GFLOP one-shot).
// ---------------------------------------------------------------------------
__global__ __launch_bounds__(256, 2) void node_mlp0(
    const float* __restrict__ x, const float* __restrict__ b0,
    const unsigned short* __restrict__ wp, unsigned short* __restrict__ yab) {
  __shared__ uint4 ldsv2[1024];               // 16384 B
  unsigned char* lds = (unsigned char*)ldsv2;
  const int tid = threadIdx.x;
  const int lane = tid & 63;
  const int w = tid >> 6;
  const int l31 = lane & 31, h = lane >> 5;
  const int n0 = blockIdx.x * 32;

  {
    const int r = tid >> 3, p = tid & 7;
    int node = n0 + r; if (node > N_NODES - 1) node = N_NODES - 1;
    const float* s = x + (size_t)node * 256 + p * 32;
    const unsigned rowb = (unsigned)r * 512;
    const unsigned sx = (unsigned)((r & 7) << 4);
#pragma unroll
    for (int c = 0; c < 4; ++c) {
      const int kk = (c + p) & 3;
      const float4 f0 = *(const float4*)(s + kk * 8);
      const float4 f1 = *(const float4*)(s + kk * 8 + 4);
      uint4 pk;
      pk.x = (unsigned)f2bf(f0.x) | ((unsigned)f2bf(f0.y) << 16);
      pk.y = (unsigned)f2bf(f0.z) | ((unsigned)f2bf(f0.w) << 16);
      pk.z = (unsigned)f2bf(f1.x) | ((unsigned)f2bf(f1.y) << 16);
      pk.w = (unsigned)f2bf(f1.z) | ((unsigned)f2bf(f1.w) << 16);
      *(uint4*)(lds + rowb + (((unsigned)(p * 64 + kk * 16)) ^ sx)) = pk;
    }
  }
  __syncthreads();

  const unsigned sx31 = (unsigned)((l31 & 7) << 4);
  const int ntb = (w & 1) * 8;
  const int ksOff = (w >> 1) * 16;

  f32x16 acc[8];
#pragma unroll
  for (int f = 0; f < 8; ++f) {
    if (w < 2) {
      const int gf = w * 8 + f;
#pragma unroll
      for (int qd = 0; qd < 4; ++qd) {
        const float4 bq = *(const float4*)(b0 + gf * 32 + 8 * qd + 4 * h);
#pragma unroll
        for (int rr = 0; rr < 4; ++rr) acc[f][4 * qd + rr] = bq[rr];
      }
    } else {
#pragma unroll
      for (int i = 0; i < 16; ++i) acc[f][i] = 0.f;
    }
  }

#pragma unroll 2
  for (int ks = 0; ks < 16; ++ks) {
    const unsigned cb = (unsigned)(ks * 32 + h * 16);
    bf16x8 e0 = *(const bf16x8*)(lds + (unsigned)l31 * 512 + (cb ^ sx31));
#pragma unroll
    for (int f = 0; f < 8; ++f) {
      const bf16x8 wf = *(const bf16x8*)(wp +
          ((size_t)(((ntb + f) * 32) + ks + ksOff) * 64 + lane) * 8);
      acc[f] = __builtin_amdgcn_mfma_f32_32x32x16_bf16(wf, e0, acc[f], 0, 0, 0);
    }
  }

  {
    int node = n0 + l31; if (node > N_NODES - 1) node = N_NODES - 1;
    unsigned short* yrow = yab + (size_t)node * 1024;
#pragma unroll
    for (int f = 0; f < 8; ++f) {
      const int gf = w * 8 + f;
#pragma unroll
      for (int reg = 0; reg < 16; ++reg) {
        const int feat = gf * 32 + (reg & 3) + 8 * (reg >> 2) + 4 * h;
        yrow[feat] = f2bf_cast(acc[f][reg]);
      }
    }
  }
}

// ===== counting-sort edges by src node ======================================
__global__ __launch_bounds__(256) void zero_hist(unsigned* __restrict__ hist) {
  int i = blockIdx.x * 256 + threadIdx.x;
  if (i < 10240) hist[i] = 0u;
}
__global__ __launch_bounds__(256) void hist_src(
    const int* __restrict__ eidx, unsigned* __restrict__ hist) {
  int e = blockIdx.x * 256 + threadIdx.x;
  if (e < E_TOTAL) atomicAdd(&hist[eidx[e]], 1u);
}
__global__ __launch_bounds__(1024) void scan_hist(unsigned* __restrict__ hist) {
  __shared__ unsigned part[1024];
  const int t = threadIdx.x;
  unsigned loc[10];
  unsigned s = 0;
#pragma unroll
  for (int i = 0; i < 10; ++i) {
    const int idx = t * 10 + i;
    unsigned v = (idx < N_NODES) ? hist[idx] : 0u;
    loc[i] = v; s += v;
  }
  part[t] = s;
  __syncthreads();
  for (int off = 1; off < 1024; off <<= 1) {
    unsigned v = (t >= off) ? part[t - off] : 0u;
    __syncthreads();
    part[t] += v;
    __syncthreads();
  }
  unsigned run = (t == 0) ? 0u : part[t - 1];
#pragma unroll
  for (int i = 0; i < 10; ++i) {
    const int idx = t * 10 + i;
    if (idx < N_NODES) { hist[idx] = run; run += loc[i]; }
  }
}
__global__ __launch_bounds__(256) void scatter_perm(
    const int* __restrict__ eidx, unsigned* __restrict__ hist,
    unsigned* __restrict__ perm, unsigned* __restrict__ rank) {
  int e = blockIdx.x * 256 + threadIdx.x;
  if (e < E_TOTAL) {
    unsigned pos = atomicAdd(&hist[eidx[e]], 1u);
    perm[pos] = (unsigned)e;
    rank[e] = pos;
  }
}

// ---------------------------------------------------------------------------
// Edge kernel (layer-0 factored), 8-WAVE blocks for gather-latency TLP:
// 512 threads, wave = 2 ft-tiles x 2 e-tiles (acc 4 x f32x16 = 64 AGPR),
// 2 blocks/CU -> 16 waves/CU (was 8). Staging = 16 loads/thread over 512 thr.
// SORTED=1: slots src-sorted (perm), raw per-edge out to outp[slot];
// SORTED=0: slot=e, pair-mean in-kernel. K-staggered, e-frag pipelined.
// LDS: [64][512] bf16 H0 (65536 B, swizzle byte^=(row&7)<<4) + 1280 B obuf.
// ---------------------------------------------------------------------------
template <int SORTED>
__global__ __launch_bounds__(512, 2) void edge_mlp2(
    const int* __restrict__ eidx, const unsigned* __restrict__ perm,
    const float* __restrict__ b1, const float* __restrict__ b2,
    const unsigned short* __restrict__ wp,
    const unsigned short* __restrict__ yab, float* __restrict__ dst5) {
  __shared__ uint4 ldsv[4096 + 80];           // 65536 + 1280 B
  unsigned char* lds = (unsigned char*)ldsv;
  float* obuf = (float*)(lds + 65536);        // 64*5 f32

  const int tid = threadIdx.x;
  const int lane = tid & 63;
  const int w = tid >> 6;                     // wave 0..7
  const int l31 = lane & 31, h = lane >> 5;
  const int l15 = lane & 15, q = lane >> 4;
  const unsigned t = blockIdx.x;
  const int phase = ((int)t >> 3) & 31;

  // ---- stage H0[64][512]: relu(ya[src] + yb[dst]); 8 threads/row ----
  {
    const int r = tid >> 3, p = tid & 7;
    const int s = (int)t * 64 + r;
    const int e = SORTED ? (int)perm[s] : s;
    const int src = eidx[e];
    const int dst = eidx[E_TOTAL + e];
    const unsigned short* pa = yab + (size_t)src * 1024 + p * 64;
    const unsigned short* pb = yab + (size_t)dst * 1024 + 512 + p * 64;
    const unsigned rowb = (unsigned)r * 1024;
    const unsigned sx = (unsigned)((r & 7) << 4);
    const unsigned cb0 = (unsigned)(p * 128);
#pragma unroll
    for (int i = 0; i < 8; ++i) {
      const int kk = (i + p) & 7;             // phase by p: spread banks
      const uint4 a = *(const uint4*)(pa + kk * 8);
      const uint4 b = *(const uint4*)(pb + kk * 8);
      uint4 o;
      o.x = addrelu2(a.x, b.x);
      o.y = addrelu2(a.y, b.y);
      o.z = addrelu2(a.z, b.z);
      o.w = addrelu2(a.w, b.w);
      *(uint4*)(lds + rowb + ((cb0 + (unsigned)kk * 16) ^ sx)) = o;
    }
  }
  __syncthreads();

  const unsigned sx31 = (unsigned)((l31 & 7) << 4);
  const unsigned er0 = (unsigned)l31 * 1024;
  const unsigned er1 = (unsigned)(32 + l31) * 1024;

  // ===== hidden layer 1: wave w -> feature tiles 2w, 2w+1 x all 64 edges ====
  {
    const unsigned short* wl = wp + 262144;   // W1p
    const unsigned short* wbA = wl + (size_t)(2 * w) * 16384 + (size_t)lane * 8;
    const unsigned short* wbB = wbA + 16384;

    f32x16 aA0, aA1, aB0, aB1;                // acc[ftile][etile]
#define BINIT(ACC0, ACC1, F)                                                   \
    {                                                                          \
      _Pragma("unroll")                                                        \
      for (int qd = 0; qd < 4; ++qd) {                                         \
        const float4 bq = *(const float4*)(b1 + w * 64 + (F) * 32 + 8 * qd + 4 * h); \
        _Pragma("unroll")                                                      \
        for (int rr = 0; rr < 4; ++rr) {                                       \
          (ACC0)[4 * qd + rr] = bq[rr];                                        \
          (ACC1)[4 * qd + rr] = bq[rr];                                        \
        }                                                                      \
      }                                                                        \
    }
    BINIT(aA0, aA1, 0) BINIT(aB0, aB1, 1)
#undef BINIT

    bf16x8 cwA = *(const bf16x8*)(wbA + phase * 512);
    bf16x8 cwB = *(const bf16x8*)(wbB + phase * 512);
    const unsigned cb00 = (unsigned)(phase * 32 + h * 16);
    bf16x8 e0 = *(const bf16x8*)(lds + er0 + (cb00 ^ sx31));
    bf16x8 e1 = *(const bf16x8*)(lds + er1 + (cb00 ^ sx31));

#pragma unroll 2
    for (int i = 0; i < 32; ++i) {
      const int ks = (i + phase) & 31;
      const int kp = (ks + 1) & 31;
      bf16x8 nwA = *(const bf16x8*)(wbA + kp * 512);
      bf16x8 nwB = *(const bf16x8*)(wbB + kp * 512);
      const unsigned cbn = (unsigned)(kp * 32 + h * 16);
      bf16x8 ne0 = *(const bf16x8*)(lds + er0 + (cbn ^ sx31));
      bf16x8 ne1 = *(const bf16x8*)(lds + er1 + (cbn ^ sx31));
      aA0 = __builtin_amdgcn_mfma_f32_32x32x16_bf16(cwA, e0, aA0, 0, 0, 0);
      aB0 = __builtin_amdgcn_mfma_f32_32x32x16_bf16(cwB, e0, aB0, 0, 0, 0);
      aA1 = __builtin_amdgcn_mfma_f32_32x32x16_bf16(cwA, e1, aA1, 0, 0, 0);
      aB1 = __builtin_amdgcn_mfma_f32_32x32x16_bf16(cwB, e1, aB1, 0, 0, 0);
      cwA = nwA; cwB = nwB;
      e0 = ne0; e1 = ne1;
    }

    __syncthreads();

    // relu + cvt + write H over A, b64 quads (C: col=edge, row=feature)
    // quad byte col = 128w + 64*F + 16qd + 8h, XOR (edge&7)<<4.
#define EPI_TILE(ACC, F, ET)                                                   \
    {                                                                          \
      const unsigned rowb = (unsigned)((ET) * 32 + l31) * 1024;                \
      const unsigned cbase = (unsigned)(128 * w + 64 * (F) + 8 * h);           \
      _Pragma("unroll")                                                        \
      for (int qd = 0; qd < 4; ++qd) {                                         \
        uint2 pk2;                                                             \
        pk2.x = (unsigned)f2bf_cast(fmaxf((ACC)[4 * qd + 0], 0.f)) |           \
                ((unsigned)f2bf_cast(fmaxf((ACC)[4 * qd + 1], 0.f)) << 16);    \
        pk2.y = (unsigned)f2bf_cast(fmaxf((ACC)[4 * qd + 2], 0.f)) |           \
                ((unsigned)f2bf_cast(fmaxf((ACC)[4 * qd + 3], 0.f)) << 16);    \
        *(uint2*)(lds + rowb + ((cbase + 16u * qd) ^ sx31)) = pk2;             \
      }                                                                        \
    }
    EPI_TILE(aA0, 0, 0) EPI_TILE(aA1, 0, 1)
    EPI_TILE(aB0, 1, 0) EPI_TILE(aB1, 1, 1)
#undef EPI_TILE
    __syncthreads();
  }

  // ===== layer 2: waves 0..3 -> slots w*16..+15 =====
  if (w < 4) {
    f32x4 acc2; acc2[0] = 0.f; acc2[1] = 0.f; acc2[2] = 0.f; acc2[3] = 0.f;
    const unsigned short* w2b = wp + 524288 + (size_t)lane * 8;
    const unsigned row = (unsigned)(w * 16 + l15);
    const unsigned rsx = (row & 7) << 4;
    const int ph16 = phase & 15;
#pragma unroll
    for (int i = 0; i < 16; ++i) {
      const int k0 = (i + ph16) & 15;
      bf16x8 eF = *(const bf16x8*)(lds + row * 1024 + (((unsigned)(k0 * 64 + q * 16)) ^ rsx));
      bf16x8 wF = *(const bf16x8*)(w2b + k0 * 512);
      acc2 = __builtin_amdgcn_mfma_f32_16x16x32_bf16(wF, eF, acc2, 0, 0, 0);
    }
    const int e = w * 16 + l15;                // block-local slot
    if (SORTED) {
#pragma unroll
      for (int r = 0; r < 4; ++r) {
        if (q == 0) obuf[e * OUTD + r] = acc2[r] + b2[r];
        else if (q == 1 && r == 0) obuf[e * OUTD + 4] = acc2[0] + b2[4];
      }
    } else {
#pragma unroll
      for (int r = 0; r < 4; ++r) {
        const float s = __shfl_xor(acc2[r], 1);
        const float m = 0.5f * (acc2[r] + s);
        if (q == 0) obuf[e * OUTD + r] = m + b2[r];
        else if (q == 1 && r == 0) obuf[e * OUTD + 4] = m + b2[4];
      }
    }
  }
  __syncthreads();

  // ===== coalesced store (20 full 64B lines) to outp (SORTED) or out =====
  {
    uint4* dst = (uint4*)(dst5 + (size_t)t * 320);
    const uint4* sob = (const uint4*)obuf;
    if (tid < 80) dst[tid] = sob[tid];
  }
}

// pair-mean epilogue: out[2m] = out[2m+1] = 0.5*(outp[rank[2m]]+outp[rank[2m+1]])
__global__ __launch_bounds__(256) void mean_pairs(
    const unsigned* __restrict__ rank, const float* __restrict__ outp,
    float* __restrict__ out) {
  int m = blockIdx.x * 256 + threadIdx.x;
  if (m < NPAIR) {
    const float* p0 = outp + (size_t)rank[2 * m] * OUTD;
    const float* p1 = outp + (size_t)rank[2 * m + 1] * OUTD;
    float v[OUTD];
#pragma unroll
    for (int i = 0; i < OUTD; ++i) v[i] = 0.5f * (p0[i] + p1[i]);
    float* o = out + (size_t)m * 2 * OUTD;
#pragma unroll
    for (int i = 0; i < OUTD; ++i) { o[i] = v[i]; o[OUTD + i] = v[i]; }
  }
}

extern "C" void kernel_launch(void* const* d_in, const int* in_sizes, int n_in,
                              void* d_out, int out_size, void* d_ws, size_t ws_size,
                              hipStream_t stream) {
  const float* x  = (const float*)d_in[0];
  const int* eidx = (const int*)d_in[1];
  const float* W0 = (const float*)d_in[2];
  const float* b0 = (const float*)d_in[3];
  const float* W1 = (const float*)d_in[4];
  const float* b1 = (const float*)d_in[5];
  const float* W2 = (const float*)d_in[6];
  const float* b2 = (const float*)d_in[7];
  float* out = (float*)d_out;
  unsigned short* wp = (unsigned short*)d_ws;
  if (ws_size < WS_Y) return;                 // need yab workspace

  pack_weights<<<2080, 256, 0, stream>>>(W0, W1, W2, wp);
  unsigned short* yab = wp + WP_USHORTS;
  node_mlp0<<<313, 256, 0, stream>>>(x, b0, wp, yab);

  if (ws_size >= WS_SORT) {
    unsigned char* base = (unsigned char*)d_ws + WS_Y;
    unsigned* hist = (unsigned*)base;                     // 10240 u32
    unsigned* perm = (unsigned*)(base + 40960);           // 200000 u32
    unsigned* rank = (unsigned*)(base + 40960 + 800000);  // 200000 u32
    float* outp = (float*)(base + 40960 + 1600000);       // 1e6 f32

    zero_hist<<<40, 256, 0, stream>>>(hist);
    hist_src<<<782, 256, 0, stream>>>(eidx, hist);
    scan_hist<<<1, 1024, 0, stream>>>(hist);
    scatter_perm<<<782, 256, 0, stream>>>(eidx, hist, perm, rank);
    edge_mlp2<1><<<NTILES, 512, 0, stream>>>(eidx, perm, b1, b2, wp, yab, outp);
    mean_pairs<<<391, 256, 0, stream>>>(rank, outp, out);
  } else {
    edge_mlp2<0><<<NTILES, 512, 0, stream>>>(eidx, nullptr, b1, b2, wp, yab, out);
  }
}

// Round 22
// 217.744 us; speedup vs baseline: 1.3189x; 1.0067x over previous
//
#include <hip/hip_runtime.h>

#define E_TOTAL 200000
#define NPAIR 100000
#define N_NODES 10000
#define OUTD 5
#define NTILES 3125           // 200000 / 64 exactly
#define WP_USHORTS 532480     // W0p (262144) + W1p (262144) + W2p (8192)
#define YAB_USHORTS 10240000  // 10000 nodes x 1024 (ya|yb) bf16
#define WS_Y ((size_t)(WP_USHORTS + YAB_USHORTS) * 2)
// sort extras (bytes, after yab): hist u32[10240] | perm u32[200000] |
// rank u32[200000] | outp f32[1000000]
#define WS_SORT (WS_Y + 40960 + 800000 + 800000 + 4000000)

typedef __attribute__((ext_vector_type(4))) float f32x4;
typedef __attribute__((ext_vector_type(16))) float f32x16;
typedef __attribute__((ext_vector_type(8))) __bf16 bf16x8;

static __device__ __forceinline__ unsigned short f2bf(float f) {
  union { float f; unsigned u; } v; v.f = f;
  unsigned u = v.u;
  unsigned r = (u + 0x7FFFu + ((u >> 16) & 1u)) >> 16;   // RNE
  return (unsigned short)r;
}
static __device__ __forceinline__ unsigned short f2bf_cast(float f) {
  __bf16 h = (__bf16)f;                                   // HW cvt, RNE
  return __builtin_bit_cast(unsigned short, h);
}
static __device__ __forceinline__ unsigned addrelu2(unsigned a, unsigned b) {
  float alo = __builtin_bit_cast(float, a << 16);
  float ahi = __builtin_bit_cast(float, a & 0xffff0000u);
  float blo = __builtin_bit_cast(float, b << 16);
  float bhi = __builtin_bit_cast(float, b & 0xffff0000u);
  float slo = fmaxf(alo + blo, 0.f);
  float shi = fmaxf(ahi + bhi, 0.f);
  return (unsigned)f2bf_cast(slo) | ((unsigned)f2bf_cast(shi) << 16);
}

// ---------------------------------------------------------------------------
// Pack W0,W1 [512x512] into 32x32x16-bf16 fragment order; W2 padded N=16.
// RESTRUCTURED: one thread = one 16B packed chunk (8 coalesced f32 reads ->
// 1 coalesced uint4 store). Thread map: tid<65536 -> (sel, ntile, ks, lane);
// value = W[k][n], k = ks*16 + (lane>>5)*8 + j, n = ntile*32 + (lane&31).
// tid in [65536,66560) -> W2 chunks (k0, lane). tid in [66560,76800) -> zero
// hist (folded; only when hist != nullptr).
// ---------------------------------------------------------------------------
__global__ __launch_bounds__(256) void pack_weights(
    const float* __restrict__ W0, const float* __restrict__ W1,
    const float* __restrict__ W2, unsigned short* __restrict__ wp,
    unsigned* __restrict__ hist) {
  const int tid = blockIdx.x * 256 + threadIdx.x;
  if (tid < 65536) {
    const int sel = tid >> 15;
    const int r = tid & 32767;
    const int ntile = r >> 11;                 // 0..15
    const int ks = (r >> 6) & 31;              // 0..31
    const int lane = r & 63;
    const float* W = sel ? W1 : W0;
    const int n = ntile * 32 + (lane & 31);
    const int kb = ks * 16 + ((lane >> 5) << 3);
    uint4 pk;
    pk.x = (unsigned)f2bf(W[(kb + 0) * 512 + n]) | ((unsigned)f2bf(W[(kb + 1) * 512 + n]) << 16);
    pk.y = (unsigned)f2bf(W[(kb + 2) * 512 + n]) | ((unsigned)f2bf(W[(kb + 3) * 512 + n]) << 16);
    pk.z = (unsigned)f2bf(W[(kb + 4) * 512 + n]) | ((unsigned)f2bf(W[(kb + 5) * 512 + n]) << 16);
    pk.w = (unsigned)f2bf(W[(kb + 6) * 512 + n]) | ((unsigned)f2bf(W[(kb + 7) * 512 + n]) << 16);
    *(uint4*)(wp + (size_t)sel * 262144 +
              (((size_t)(ntile * 32 + ks) * 64 + lane) << 3)) = pk;
  } else if (tid < 66560) {                    // W2 padded N=5 -> 16
    const int r = tid - 65536;
    const int k0 = r >> 6, lane = r & 63;
    const int kb = k0 * 32 + ((lane >> 4) << 3);
    const int n = lane & 15;
    unsigned short v[8];
#pragma unroll
    for (int j = 0; j < 8; ++j)
      v[j] = (n < OUTD) ? f2bf(W2[(kb + j) * OUTD + n]) : (unsigned short)0;
    uint4 pk;
    pk.x = (unsigned)v[0] | ((unsigned)v[1] << 16);
    pk.y = (unsigned)v[2] | ((unsigned)v[3] << 16);
    pk.z = (unsigned)v[4] | ((unsigned)v[5] << 16);
    pk.w = (unsigned)v[6] | ((unsigned)v[7] << 16);
    *(uint4*)(wp + 524288 + (((size_t)k0 * 64 + lane) << 3)) = pk;
  } else if (tid < 76800) {
    if (hist) hist[tid - 66560] = 0u;          // folded zero_hist
  }
}

// ---------------------------------------------------------------------------
// Node-level layer-0 precompute; packed uint2 stores (4 feats/store).
// yab[node][0..512) = x@W0a + b0 ; [512..1024) = x@W0b.
// ---------------------------------------------------------------------------
__global__ __launch_bounds__(256, 2) void node_mlp0(
    const float* __restrict__ x, const float* __restrict__ b0,
    const unsigned short* __restrict__ wp, unsigned short* __restrict__ yab) {
  __shared__ uint4 ldsv2[1024];               // 16384 B
  unsigned char* lds = (unsigned char*)ldsv2;
  const int tid = threadIdx.x;
  const int lane = tid & 63;
  const int w = tid >> 6;
  const int l31 = lane & 31, h = lane >> 5;
  const int n0 = blockIdx.x * 32;

  {
    const int r = tid >> 3, p = tid & 7;
    int node = n0 + r; if (node > N_NODES - 1) node = N_NODES - 1;
    const float* s = x + (size_t)node * 256 + p * 32;
    const unsigned rowb = (unsigned)r * 512;
    const unsigned sx = (unsigned)((r & 7) << 4);
#pragma unroll
    for (int c = 0; c < 4; ++c) {
      const int kk = (c + p) & 3;
      const float4 f0 = *(const float4*)(s + kk * 8);
      const float4 f1 = *(const float4*)(s + kk * 8 + 4);
      uint4 pk;
      pk.x = (unsigned)f2bf(f0.x) | ((unsigned)f2bf(f0.y) << 16);
      pk.y = (unsigned)f2bf(f0.z) | ((unsigned)f2bf(f0.w) << 16);
      pk.z = (unsigned)f2bf(f1.x) | ((unsigned)f2bf(f1.y) << 16);
      pk.w = (unsigned)f2bf(f1.z) | ((unsigned)f2bf(f1.w) << 16);
      *(uint4*)(lds + rowb + (((unsigned)(p * 64 + kk * 16)) ^ sx)) = pk;
    }
  }
  __syncthreads();

  const unsigned sx31 = (unsigned)((l31 & 7) << 4);
  const int ntb = (w & 1) * 8;
  const int ksOff = (w >> 1) * 16;

  f32x16 acc[8];
#pragma unroll
  for (int f = 0; f < 8; ++f) {
    if (w < 2) {
      const int gf = w * 8 + f;
#pragma unroll
      for (int qd = 0; qd < 4; ++qd) {
        const float4 bq = *(const float4*)(b0 + gf * 32 + 8 * qd + 4 * h);
#pragma unroll
        for (int rr = 0; rr < 4; ++rr) acc[f][4 * qd + rr] = bq[rr];
      }
    } else {
#pragma unroll
      for (int i = 0; i < 16; ++i) acc[f][i] = 0.f;
    }
  }

#pragma unroll 2
  for (int ks = 0; ks < 16; ++ks) {
    const unsigned cb = (unsigned)(ks * 32 + h * 16);
    bf16x8 e0 = *(const bf16x8*)(lds + (unsigned)l31 * 512 + (cb ^ sx31));
#pragma unroll
    for (int f = 0; f < 8; ++f) {
      const bf16x8 wf = *(const bf16x8*)(wp +
          ((size_t)(((ntb + f) * 32) + ks + ksOff) * 64 + lane) * 8);
      acc[f] = __builtin_amdgcn_mfma_f32_32x32x16_bf16(wf, e0, acc[f], 0, 0, 0);
    }
  }

  // packed store: C reg quad (4qd..4qd+3) = feats gf*32+8qd+4h+0..3 -> uint2
  {
    int node = n0 + l31; if (node > N_NODES - 1) node = N_NODES - 1;
    unsigned short* yrow = yab + (size_t)node * 1024;
#pragma unroll
    for (int f = 0; f < 8; ++f) {
      const int gf = w * 8 + f;
#pragma unroll
      for (int qd = 0; qd < 4; ++qd) {
        uint2 pk;
        pk.x = (unsigned)f2bf_cast(acc[f][4 * qd + 0]) |
               ((unsigned)f2bf_cast(acc[f][4 * qd + 1]) << 16);
        pk.y = (unsigned)f2bf_cast(acc[f][4 * qd + 2]) |
               ((unsigned)f2bf_cast(acc[f][4 * qd + 3]) << 16);
        *(uint2*)(yrow + gf * 32 + 8 * qd + 4 * h) = pk;
      }
    }
  }
}

// ===== counting-sort edges by src node ======================================
__global__ __launch_bounds__(256) void hist_src(
    const int* __restrict__ eidx, unsigned* __restrict__ hist) {
  int e = blockIdx.x * 256 + threadIdx.x;
  if (e < E_TOTAL) atomicAdd(&hist[eidx[e]], 1u);
}
__global__ __launch_bounds__(1024) void scan_hist(unsigned* __restrict__ hist) {
  __shared__ unsigned part[1024];
  const int t = threadIdx.x;
  unsigned loc[10];
  unsigned s = 0;
#pragma unroll
  for (int i = 0; i < 10; ++i) {
    const int idx = t * 10 + i;
    unsigned v = (idx < N_NODES) ? hist[idx] : 0u;
    loc[i] = v; s += v;
  }
  part[t] = s;
  __syncthreads();
  for (int off = 1; off < 1024; off <<= 1) {
    unsigned v = (t >= off) ? part[t - off] : 0u;
    __syncthreads();
    part[t] += v;
    __syncthreads();
  }
  unsigned run = (t == 0) ? 0u : part[t - 1];
#pragma unroll
  for (int i = 0; i < 10; ++i) {
    const int idx = t * 10 + i;
    if (idx < N_NODES) { hist[idx] = run; run += loc[i]; }
  }
}
__global__ __launch_bounds__(256) void scatter_perm(
    const int* __restrict__ eidx, unsigned* __restrict__ hist,
    unsigned* __restrict__ perm, unsigned* __restrict__ rank) {
  int e = blockIdx.x * 256 + threadIdx.x;
  if (e < E_TOTAL) {
    unsigned pos = atomicAdd(&hist[eidx[e]], 1u);
    perm[pos] = (unsigned)e;
    rank[e] = pos;
  }
}

// ---------------------------------------------------------------------------
// Edge kernel (layer-0 factored), 8-wave blocks, 2 blocks/CU (16 waves/CU).
// Identical to R21 (proven): wave = 2 ft-tiles x 2 e-tiles, K-staggered,
// e-frag pipelined. SORTED=1: slots src-sorted (perm), raw out to outp;
// SORTED=0: slot=e, pair-mean in-kernel.
// ---------------------------------------------------------------------------
template <int SORTED>
__global__ __launch_bounds__(512, 2) void edge_mlp2(
    const int* __restrict__ eidx, const unsigned* __restrict__ perm,
    const float* __restrict__ b1, const float* __restrict__ b2,
    const unsigned short* __restrict__ wp,
    const unsigned short* __restrict__ yab, float* __restrict__ dst5) {
  __shared__ uint4 ldsv[4096 + 80];           // 65536 + 1280 B
  unsigned char* lds = (unsigned char*)ldsv;
  float* obuf = (float*)(lds + 65536);        // 64*5 f32

  const int tid = threadIdx.x;
  const int lane = tid & 63;
  const int w = tid >> 6;                     // wave 0..7
  const int l31 = lane & 31, h = lane >> 5;
  const int l15 = lane & 15, q = lane >> 4;
  const unsigned t = blockIdx.x;
  const int phase = ((int)t >> 3) & 31;

  // ---- stage H0[64][512]: relu(ya[src] + yb[dst]); 8 threads/row ----
  {
    const int r = tid >> 3, p = tid & 7;
    const int s = (int)t * 64 + r;
    const int e = SORTED ? (int)perm[s] : s;
    const int src = eidx[e];
    const int dst = eidx[E_TOTAL + e];
    const unsigned short* pa = yab + (size_t)src * 1024 + p * 64;
    const unsigned short* pb = yab + (size_t)dst * 1024 + 512 + p * 64;
    const unsigned rowb = (unsigned)r * 1024;
    const unsigned sx = (unsigned)((r & 7) << 4);
    const unsigned cb0 = (unsigned)(p * 128);
#pragma unroll
    for (int i = 0; i < 8; ++i) {
      const int kk = (i + p) & 7;             // phase by p: spread banks
      const uint4 a = *(const uint4*)(pa + kk * 8);
      const uint4 b = *(const uint4*)(pb + kk * 8);
      uint4 o;
      o.x = addrelu2(a.x, b.x);
      o.y = addrelu2(a.y, b.y);
      o.z = addrelu2(a.z, b.z);
      o.w = addrelu2(a.w, b.w);
      *(uint4*)(lds + rowb + ((cb0 + (unsigned)kk * 16) ^ sx)) = o;
    }
  }
  __syncthreads();

  const unsigned sx31 = (unsigned)((l31 & 7) << 4);
  const unsigned er0 = (unsigned)l31 * 1024;
  const unsigned er1 = (unsigned)(32 + l31) * 1024;

  // ===== hidden layer 1: wave w -> feature tiles 2w, 2w+1 x all 64 edges ====
  {
    const unsigned short* wl = wp + 262144;   // W1p
    const unsigned short* wbA = wl + (size_t)(2 * w) * 16384 + (size_t)lane * 8;
    const unsigned short* wbB = wbA + 16384;

    f32x16 aA0, aA1, aB0, aB1;                // acc[ftile][etile]
#define BINIT(ACC0, ACC1, F)                                                   \
    {                                                                          \
      _Pragma("unroll")                                                        \
      for (int qd = 0; qd < 4; ++qd) {                                         \
        const float4 bq = *(const float4*)(b1 + w * 64 + (F) * 32 + 8 * qd + 4 * h); \
        _Pragma("unroll")                                                      \
        for (int rr = 0; rr < 4; ++rr) {                                       \
          (ACC0)[4 * qd + rr] = bq[rr];                                        \
          (ACC1)[4 * qd + rr] = bq[rr];                                        \
        }                                                                      \
      }                                                                        \
    }
    BINIT(aA0, aA1, 0) BINIT(aB0, aB1, 1)
#undef BINIT

    bf16x8 cwA = *(const bf16x8*)(wbA + phase * 512);
    bf16x8 cwB = *(const bf16x8*)(wbB + phase * 512);
    const unsigned cb00 = (unsigned)(phase * 32 + h * 16);
    bf16x8 e0 = *(const bf16x8*)(lds + er0 + (cb00 ^ sx31));
    bf16x8 e1 = *(const bf16x8*)(lds + er1 + (cb00 ^ sx31));

#pragma unroll 2
    for (int i = 0; i < 32; ++i) {
      const int ks = (i + phase) & 31;
      const int kp = (ks + 1) & 31;
      bf16x8 nwA = *(const bf16x8*)(wbA + kp * 512);
      bf16x8 nwB = *(const bf16x8*)(wbB + kp * 512);
      const unsigned cbn = (unsigned)(kp * 32 + h * 16);
      bf16x8 ne0 = *(const bf16x8*)(lds + er0 + (cbn ^ sx31));
      bf16x8 ne1 = *(const bf16x8*)(lds + er1 + (cbn ^ sx31));
      aA0 = __builtin_amdgcn_mfma_f32_32x32x16_bf16(cwA, e0, aA0, 0, 0, 0);
      aB0 = __builtin_amdgcn_mfma_f32_32x32x16_bf16(cwB, e0, aB0, 0, 0, 0);
      aA1 = __builtin_amdgcn_mfma_f32_32x32x16_bf16(cwA, e1, aA1, 0, 0, 0);
      aB1 = __builtin_amdgcn_mfma_f32_32x32x16_bf16(cwB, e1, aB1, 0, 0, 0);
      cwA = nwA; cwB = nwB;
      e0 = ne0; e1 = ne1;
    }

    __syncthreads();

    // relu + cvt + write H over A, b64 quads (C: col=edge, row=feature)
#define EPI_TILE(ACC, F, ET)                                                   \
    {                                                                          \
      const unsigned rowb = (unsigned)((ET) * 32 + l31) * 1024;                \
      const unsigned cbase = (unsigned)(128 * w + 64 * (F) + 8 * h);           \
      _Pragma("unroll")                                                        \
      for (int qd = 0; qd < 4; ++qd) {                                         \
        uint2 pk2;                                                             \
        pk2.x = (unsigned)f2bf_cast(fmaxf((ACC)[4 * qd + 0], 0.f)) |           \
                ((unsigned)f2bf_cast(fmaxf((ACC)[4 * qd + 1], 0.f)) << 16);    \
        pk2.y = (unsigned)f2bf_cast(fmaxf((ACC)[4 * qd + 2], 0.f)) |           \
                ((unsigned)f2bf_cast(fmaxf((ACC)[4 * qd + 3], 0.f)) << 16);    \
        *(uint2*)(lds + rowb + ((cbase + 16u * qd) ^ sx31)) = pk2;             \
      }                                                                        \
    }
    EPI_TILE(aA0, 0, 0) EPI_TILE(aA1, 0, 1)
    EPI_TILE(aB0, 1, 0) EPI_TILE(aB1, 1, 1)
#undef EPI_TILE
    __syncthreads();
  }

  // ===== layer 2: waves 0..3 -> slots w*16..+15 =====
  if (w < 4) {
    f32x4 acc2; acc2[0] = 0.f; acc2[1] = 0.f; acc2[2] = 0.f; acc2[3] = 0.f;
    const unsigned short* w2b = wp + 524288 + (size_t)lane * 8;
    const unsigned row = (unsigned)(w * 16 + l15);
    const unsigned rsx = (row & 7) << 4;
    const int ph16 = phase & 15;
#pragma unroll
    for (int i = 0; i < 16; ++i) {
      const int k0 = (i + ph16) & 15;
      bf16x8 eF = *(const bf16x8*)(lds + row * 1024 + (((unsigned)(k0 * 64 + q * 16)) ^ rsx));
      bf16x8 wF = *(const bf16x8*)(w2b + k0 * 512);
      acc2 = __builtin_amdgcn_mfma_f32_16x16x32_bf16(wF, eF, acc2, 0, 0, 0);
    }
    const int e = w * 16 + l15;                // block-local slot
    if (SORTED) {
#pragma unroll
      for (int r = 0; r < 4; ++r) {
        if (q == 0) obuf[e * OUTD + r] = acc2[r] + b2[r];
        else if (q == 1 && r == 0) obuf[e * OUTD + 4] = acc2[0] + b2[4];
      }
    } else {
#pragma unroll
      for (int r = 0; r < 4; ++r) {
        const float s = __shfl_xor(acc2[r], 1);
        const float m = 0.5f * (acc2[r] + s);
        if (q == 0) obuf[e * OUTD + r] = m + b2[r];
        else if (q == 1 && r == 0) obuf[e * OUTD + 4] = m + b2[4];
      }
    }
  }
  __syncthreads();

  // ===== coalesced store (20 full 64B lines) to outp (SORTED) or out =====
  {
    uint4* dst = (uint4*)(dst5 + (size_t)t * 320);
    const uint4* sob = (const uint4*)obuf;
    if (tid < 80) dst[tid] = sob[tid];
  }
}

// pair-mean epilogue: out[2m] = out[2m+1] = 0.5*(outp[rank[2m]]+outp[rank[2m+1]])
__global__ __launch_bounds__(256) void mean_pairs(
    const unsigned* __restrict__ rank, const float* __restrict__ outp,
    float* __restrict__ out) {
  int m = blockIdx.x * 256 + threadIdx.x;
  if (m < NPAIR) {
    const float* p0 = outp + (size_t)rank[2 * m] * OUTD;
    const float* p1 = outp + (size_t)rank[2 * m + 1] * OUTD;
    float v[OUTD];
#pragma unroll
    for (int i = 0; i < OUTD; ++i) v[i] = 0.5f * (p0[i] + p1[i]);
    float* o = out + (size_t)m * 2 * OUTD;
#pragma unroll
    for (int i = 0; i < OUTD; ++i) { o[i] = v[i]; o[OUTD + i] = v[i]; }
  }
}

extern "C" void kernel_launch(void* const* d_in, const int* in_sizes, int n_in,
                              void* d_out, int out_size, void* d_ws, size_t ws_size,
                              hipStream_t stream) {
  const float* x  = (const float*)d_in[0];
  const int* eidx = (const int*)d_in[1];
  const float* W0 = (const float*)d_in[2];
  const float* b0 = (const float*)d_in[3];
  const float* W1 = (const float*)d_in[4];
  const float* b1 = (const float*)d_in[5];
  const float* W2 = (const float*)d_in[6];
  const float* b2 = (const float*)d_in[7];
  float* out = (float*)d_out;
  unsigned short* wp = (unsigned short*)d_ws;
  if (ws_size < WS_Y) return;                 // need yab workspace

  const bool sorted = (ws_size >= WS_SORT);
  unsigned char* base = (unsigned char*)d_ws + WS_Y;
  unsigned* hist = sorted ? (unsigned*)base : nullptr;

  pack_weights<<<300, 256, 0, stream>>>(W0, W1, W2, wp, hist);
  unsigned short* yab = wp + WP_USHORTS;
  node_mlp0<<<313, 256, 0, stream>>>(x, b0, wp, yab);

  if (sorted) {
    unsigned* perm = (unsigned*)(base + 40960);           // 200000 u32
    unsigned* rank = (unsigned*)(base + 40960 + 800000);  // 200000 u32
    float* outp = (float*)(base + 40960 + 1600000);       // 1e6 f32

    hist_src<<<782, 256, 0, stream>>>(eidx, hist);
    scan_hist<<<1, 1024, 0, stream>>>(hist);
    scatter_perm<<<782, 256, 0, stream>>>(eidx, hist, perm, rank);
    edge_mlp2<1><<<NTILES, 512, 0, stream>>>(eidx, perm, b1, b2, wp, yab, outp);
    mean_pairs<<<391, 256, 0, stream>>>(rank, outp, out);
  } else {
    edge_mlp2<0><<<NTILES, 512, 0, stream>>>(eidx, nullptr, b1, b2, wp, yab, out);
  }
}